// Round 1
// baseline (1702.408 us; speedup 1.0000x reference)
//
#include <hip/hip_runtime.h>
#include <math.h>

// ---------------------------------------------------------------------------
// Model: conv1(5x5,20)+pool2 -> conv2(5x5,50)+pool2 -> pcaps(5x5 pad2,16)
//        -> squash -> priors -> dynamic routing(3) -> fc1(relu) -> fc2
// B=2048. All fp32.
// ---------------------------------------------------------------------------

#define BATCH 2048

__device__ inline float wave_sum(float v) {
#pragma unroll
    for (int off = 32; off >= 1; off >>= 1) v += __shfl_xor(v, off);
    return v;
}
__device__ inline float wave_max(float v) {
#pragma unroll
    for (int off = 32; off >= 1; off >>= 1) v = fmaxf(v, __shfl_xor(v, off));
    return v;
}

// ---------- Kernel 1: conv1+pool2 + conv2+pool2, one block per batch -------
// x:[B,1,36,60] w1:[20,1,5,5] b1:[20] w2:[50,20,5,5] b2:[50]
// h_out:[B,3600]  (layout oc*72 + ph*12 + pw, i.e. [50,6,12] flattened)
__global__ __launch_bounds__(256) void k_convs(
    const float* __restrict__ x, const float* __restrict__ w1,
    const float* __restrict__ b1, const float* __restrict__ w2,
    const float* __restrict__ b2, float* __restrict__ h_out)
{
    __shared__ __align__(16) float xs[2160];   // 36*60
    __shared__ __align__(16) float w1s[500];   // 20*25
    __shared__ __align__(16) float h1s[8960];  // 20*16*28
    const int t = threadIdx.x;
    const int b = blockIdx.x;
    const float* xb = x + b * 2160;
    for (int i = t; i < 2160; i += 256) xs[i] = xb[i];
    for (int i = t; i < 500; i += 256) w1s[i] = w1[i];
    __syncthreads();

    // conv1 (valid 5x5) + maxpool2 -> h1s[20][16][28]
    for (int i = t; i < 8960; i += 256) {
        int oc  = i / 448;           // 16*28
        int rem = i - oc * 448;
        int ph  = rem / 28;
        int pw  = rem - ph * 28;
        int y0 = 2 * ph, x0 = 2 * pw;
        float win[6][6];
#pragma unroll
        for (int r = 0; r < 6; ++r)
#pragma unroll
            for (int s = 0; s < 6; ++s)
                win[r][s] = xs[(y0 + r) * 60 + x0 + s];
        const float* wr = &w1s[oc * 25];
        float bias = b1[oc];
        float a00 = bias, a01 = bias, a10 = bias, a11 = bias;
#pragma unroll
        for (int r = 0; r < 5; ++r)
#pragma unroll
            for (int s = 0; s < 5; ++s) {
                float w = wr[r * 5 + s];
                a00 += win[r][s] * w;
                a01 += win[r][s + 1] * w;
                a10 += win[r + 1][s] * w;
                a11 += win[r + 1][s + 1] * w;
            }
        h1s[i] = fmaxf(fmaxf(a00, a01), fmaxf(a10, a11));
    }
    __syncthreads();

    // conv2 (valid 5x5, 20 in-ch) + maxpool2 -> h_out[b][50*6*12]
    for (int i = t; i < 3600; i += 256) {
        int oc  = i / 72;
        int rem = i - oc * 72;
        int ph  = rem / 12;
        int pw  = rem - ph * 12;
        float bias = b2[oc];
        float a00 = bias, a01 = bias, a10 = bias, a11 = bias;
        const float* w2o = w2 + oc * 500;  // [20][25]
        for (int ic = 0; ic < 20; ++ic) {
            float win[6][6];
#pragma unroll
            for (int r = 0; r < 6; ++r) {
                // index is even: ic*448 + (2ph+r)*28 + 2pw  -> float2 loads
                const float2* p2 =
                    (const float2*)&h1s[ic * 448 + (2 * ph + r) * 28 + 2 * pw];
                float2 v0 = p2[0], v1 = p2[1], v2 = p2[2];
                win[r][0] = v0.x; win[r][1] = v0.y; win[r][2] = v1.x;
                win[r][3] = v1.y; win[r][4] = v2.x; win[r][5] = v2.y;
            }
            const float* wrow = w2o + ic * 25;
            float wreg[25];
#pragma unroll
            for (int j = 0; j < 25; ++j) wreg[j] = wrow[j];
#pragma unroll
            for (int r = 0; r < 5; ++r)
#pragma unroll
                for (int s = 0; s < 5; ++s) {
                    float w = wreg[r * 5 + s];
                    a00 += win[r][s] * w;
                    a01 += win[r][s + 1] * w;
                    a10 += win[r + 1][s] * w;
                    a11 += win[r + 1][s + 1] * w;
                }
        }
        h_out[b * 3600 + i] = fmaxf(fmaxf(a00, a01), fmaxf(a10, a11));
    }
}

// ---------- Kernel 2: pcaps conv(pad2) + squash + priors -------------------
// h:[B,3600] pw:[16,50,5,5] pb:[16] rw:[2,288,4,1]
// priors:[2,B,288]
__global__ __launch_bounds__(256) void k_pcaps(
    const float* __restrict__ h, const float* __restrict__ pcw,
    const float* __restrict__ pcb, const float* __restrict__ rw,
    float* __restrict__ priors)
{
    __shared__ float hs[3600];
    __shared__ float ps[1152];  // 16*6*12
    const int t = threadIdx.x;
    const int b = blockIdx.x;
    for (int i = t; i < 3600; i += 256) hs[i] = h[b * 3600 + i];
    __syncthreads();

    for (int i = t; i < 1152; i += 256) {
        int ch  = i / 72;
        int rem = i - ch * 72;
        int y   = rem / 12;
        int x   = rem - y * 12;
        float acc = pcb[ch];
        int r0 = max(0, 2 - y), r1 = min(5, 8 - y);   // iy = y+r-2 in [0,6)
        int s0 = max(0, 2 - x), s1 = min(5, 14 - x);  // ix = x+s-2 in [0,12)
        for (int ic = 0; ic < 50; ++ic) {
            const float* hsc = &hs[ic * 72];
            const float* wr  = &pcw[(ch * 50 + ic) * 25];
            for (int r = r0; r < r1; ++r) {
                int iy = y + r - 2;
                for (int s = s0; s < s1; ++s)
                    acc += hsc[iy * 12 + x + s - 2] * wr[r * 5 + s];
            }
        }
        ps[i] = acc;
    }
    __syncthreads();

    // u[b][r][c] = ps[(c*4 + r/72)*72 + r%72]; squash over c; priors
    for (int r = t; r < 288; r += 256) {
        int sub = r / 72;
        int pos = r - sub * 72;
        float u0 = ps[(0 * 4 + sub) * 72 + pos];
        float u1 = ps[(1 * 4 + sub) * 72 + pos];
        float u2 = ps[(2 * 4 + sub) * 72 + pos];
        float u3 = ps[(3 * 4 + sub) * 72 + pos];
        float n2 = u0 * u0 + u1 * u1 + u2 * u2 + u3 * u3;
        float scale = (n2 / (1.0f + n2)) * rsqrtf(n2);
        u0 *= scale; u1 *= scale; u2 *= scale; u3 *= scale;
#pragma unroll
        for (int k = 0; k < 2; ++k) {
            const float* w = &rw[(k * 288 + r) * 4];
            priors[(k * BATCH + b) * 288 + r] =
                u0 * w[0] + u1 * w[1] + u2 * w[2] + u3 * w[3];
        }
    }
}

// ---------- Kernel 3: dynamic routing (3 iters), one wave per (k,b) --------
// priors:[2,B,288] -> c:[B,2]  (c[b*2+k] = v[k,b])
__global__ __launch_bounds__(256) void k_route(
    const float* __restrict__ priors, float* __restrict__ c)
{
    int wg   = blockIdx.x * 4 + (threadIdx.x >> 6);
    int lane = threadIdx.x & 63;
    int b = wg >> 1, k = wg & 1;
    const float* pr = priors + (k * BATCH + b) * 288;
    float p[5];
    bool  val[5];
#pragma unroll
    for (int j = 0; j < 5; ++j) {
        int r  = j * 64 + lane;
        val[j] = r < 288;
        p[j]   = val[j] ? pr[r] : 0.0f;
    }
    // iter 0: uniform probs
    float tot = wave_sum(p[0] + p[1] + p[2] + p[3] + p[4]);
    float s = tot * (1.0f / 288.0f);
    float a = s * fabsf(s) / (1.0f + s * s);  // squash of scalar
#pragma unroll
    for (int it = 0; it < 2; ++it) {
        float l[5];
        float lm = -INFINITY;
#pragma unroll
        for (int j = 0; j < 5; ++j) {
            l[j] = val[j] ? p[j] * a : -INFINITY;
            lm   = fmaxf(lm, l[j]);
        }
        lm = wave_max(lm);
        float se = 0.f, sp = 0.f;
#pragma unroll
        for (int j = 0; j < 5; ++j) {
            float e = val[j] ? expf(l[j] - lm) : 0.f;
            se += e;
            sp += e * p[j];
        }
        se = wave_sum(se);
        sp = wave_sum(sp);
        float sv = sp / se;
        float v  = sv * fabsf(sv) / (1.0f + sv * sv);
        if (it == 0) a += v;
        else if (lane == 0) c[b * 2 + k] = v;
    }
}

// ---------- Kernel 4: fc1 GEMM  [2048,3600]x[500,3600]^T + caps cols -------
// f1[m][n] = relu( sum_k h[m][k]*W[n][k] + c0*W[n][3600] + c1*W[n][3601] + b[n] )
__global__ __launch_bounds__(256) void k_fc1(
    const float* __restrict__ h, const float* __restrict__ cc,
    const float* __restrict__ w, const float* __restrict__ bias,
    float* __restrict__ f1)
{
    __shared__ __align__(16) float As[16][64];
    __shared__ __align__(16) float Bs[16][64];
    const int t  = threadIdx.x;
    const int m0 = blockIdx.x * 64;  // 32
    const int n0 = blockIdx.y * 64;  // 8 (last partial: 448..499)
    const int tx = t & 15, ty = t >> 4;
    const int lm = t >> 2;          // 0..63
    const int lk = (t & 3) * 4;     // 0,4,8,12
    float acc[4][4] = {};
    for (int k0 = 0; k0 < 3600; k0 += 16) {
        float4 av = *(const float4*)&h[(size_t)(m0 + lm) * 3600 + k0 + lk];
        int n = n0 + lm;
        float4 bv = make_float4(0.f, 0.f, 0.f, 0.f);
        if (n < 500) {
            const float* wp = &w[(size_t)n * 3602 + k0 + lk];
            float2 b0 = *(const float2*)wp;
            float2 b1 = *(const float2*)(wp + 2);
            bv = make_float4(b0.x, b0.y, b1.x, b1.y);
        }
        __syncthreads();
        As[lk + 0][lm] = av.x; As[lk + 1][lm] = av.y;
        As[lk + 2][lm] = av.z; As[lk + 3][lm] = av.w;
        Bs[lk + 0][lm] = bv.x; Bs[lk + 1][lm] = bv.y;
        Bs[lk + 2][lm] = bv.z; Bs[lk + 3][lm] = bv.w;
        __syncthreads();
#pragma unroll
        for (int kk = 0; kk < 16; ++kk) {
            float4 a4 = *(const float4*)&As[kk][ty * 4];
            float4 b4 = *(const float4*)&Bs[kk][tx * 4];
            float a[4]  = {a4.x, a4.y, a4.z, a4.w};
            float bb[4] = {b4.x, b4.y, b4.z, b4.w};
#pragma unroll
            for (int i2 = 0; i2 < 4; ++i2)
#pragma unroll
                for (int j2 = 0; j2 < 4; ++j2)
                    acc[i2][j2] += a[i2] * bb[j2];
        }
    }
#pragma unroll
    for (int i2 = 0; i2 < 4; ++i2) {
        int m = m0 + ty * 4 + i2;
        float c0 = cc[m * 2 + 0], c1 = cc[m * 2 + 1];
#pragma unroll
        for (int j2 = 0; j2 < 4; ++j2) {
            int n = n0 + tx * 4 + j2;
            if (n < 500) {
                float v = acc[i2][j2] + bias[n]
                        + c0 * w[(size_t)n * 3602 + 3600]
                        + c1 * w[(size_t)n * 3602 + 3601];
                f1[(size_t)m * 500 + n] = fmaxf(v, 0.0f);
            }
        }
    }
}

// ---------- Kernel 5: fc2, one wave per (b,j) ------------------------------
// out[b][j] = sum_{k<500} f1[b][k]*w[j][k] + y[b][0]*w[j][500] + y[b][1]*w[j][501] + bias[j]
__global__ __launch_bounds__(256) void k_fc2(
    const float* __restrict__ f1, const float* __restrict__ y,
    const float* __restrict__ w, const float* __restrict__ bias,
    float* __restrict__ out)
{
    int wg   = blockIdx.x * 4 + (threadIdx.x >> 6);
    int lane = threadIdx.x & 63;
    int b = wg >> 1, j = wg & 1;
    const float* wj = w + j * 502;
    float acc = 0.f;
    for (int k = lane; k < 500; k += 64) acc += f1[(size_t)b * 500 + k] * wj[k];
    if (lane < 2) acc += y[b * 2 + lane] * wj[500 + lane];
    acc = wave_sum(acc);
    if (lane == 0) out[b * 2 + j] = acc + bias[j];
}

// ---------------------------------------------------------------------------
extern "C" void kernel_launch(void* const* d_in, const int* in_sizes, int n_in,
                              void* d_out, int out_size, void* d_ws, size_t ws_size,
                              hipStream_t stream) {
    const float* x    = (const float*)d_in[0];
    const float* y    = (const float*)d_in[1];
    const float* c1w  = (const float*)d_in[2];
    const float* c1b  = (const float*)d_in[3];
    const float* c2w  = (const float*)d_in[4];
    const float* c2b  = (const float*)d_in[5];
    const float* pcw  = (const float*)d_in[6];
    const float* pcb  = (const float*)d_in[7];
    const float* rw   = (const float*)d_in[8];
    const float* f1w  = (const float*)d_in[9];
    const float* f1b  = (const float*)d_in[10];
    const float* f2w  = (const float*)d_in[11];
    const float* f2b  = (const float*)d_in[12];
    float* out = (float*)d_out;

    float* ws     = (float*)d_ws;
    float* h      = ws;                        // 2048*3600   = 7372800
    float* priors = h + (size_t)BATCH * 3600;  // 2*2048*288  = 1179648
    float* cbuf   = priors + 2 * BATCH * 288;  // 4096
    float* f1     = cbuf + BATCH * 2;          // 2048*500    = 1024000

    k_convs<<<BATCH, 256, 0, stream>>>(x, c1w, c1b, c2w, c2b, h);
    k_pcaps<<<BATCH, 256, 0, stream>>>(h, pcw, pcb, rw, priors);
    k_route<<<BATCH * 2 / 4, 256, 0, stream>>>(priors, cbuf);
    dim3 g4(32, 8);
    k_fc1<<<g4, 256, 0, stream>>>(h, cbuf, f1w, f1b, f1);
    k_fc2<<<BATCH * 2 / 4, 256, 0, stream>>>(f1, y, f2w, f2b, out);
}

// Round 2
// 854.393 us; speedup vs baseline: 1.9925x; 1.9925x over previous
//
#include <hip/hip_runtime.h>
#include <math.h>

// ---------------------------------------------------------------------------
// Model: conv1(5x5,20)+pool2 -> conv2(5x5,50)+pool2 -> pcaps(5x5 pad2,16)
//        -> squash -> priors -> dynamic routing(3) -> fc1(relu) -> fc2
// B=2048. All fp32 (no fp32 MFMA on CDNA4 -> vector ALU).
// ---------------------------------------------------------------------------

#define BATCH 2048

__device__ inline float wave_sum(float v) {
#pragma unroll
    for (int off = 32; off >= 1; off >>= 1) v += __shfl_xor(v, off);
    return v;
}
__device__ inline float wave_max(float v) {
#pragma unroll
    for (int off = 32; off >= 1; off >>= 1) v = fmaxf(v, __shfl_xor(v, off));
    return v;
}

// ---------- Kernel 1: conv1+pool2 + conv2+pool2, one block per batch -------
// x:[B,1,36,60] w1:[20,1,5,5] b1:[20] w2:[50,20,5,5] b2:[50]
// h_out:[B,3600]  (layout oc*72 + ph*12 + pw)
// LDS: h1s[20][16][30] (pad 28->30 breaks mod-32 stride), sbuf = union of
//      {xs[36*62] + w1s[500]} (conv1 phase) and {w2s[2][50*28]} (conv2 phase).
__global__ __launch_bounds__(256, 2) void k_convs(
    const float* __restrict__ x, const float* __restrict__ w1,
    const float* __restrict__ b1, const float* __restrict__ w2,
    const float* __restrict__ b2, float* __restrict__ h_out)
{
    __shared__ __align__(16) float h1s[20 * 480];  // 9600 floats, row stride 30
    __shared__ __align__(16) float sbuf[2800];     // xs(2232)+w1s(500) | w2s 2*1400
    float* xs  = sbuf;          // [36][62]
    float* w1s = sbuf + 2232;   // [500]
    float* w2s = sbuf;          // [2][50*28]

    const int t = threadIdx.x;
    const int b = blockIdx.x;

    // ---- stage x (pad rows 60->62) and w1 ----
    const float* xb = x + b * 2160;
    for (int i = t; i < 2160; i += 256) {
        int r = i / 60, c = i - 60 * r;
        xs[r * 62 + c] = xb[i];
    }
    for (int i = t; i < 500; i += 256) w1s[i] = w1[i];
    __syncthreads();

    // ---- conv1 + pool: units = oc(20) x y(16) x xg(4), 7 pooled cols each ----
#pragma unroll 1
    for (int u = t; u < 1280; u += 256) {
        int oc  = u >> 6;          // /64
        int rem = u & 63;
        int y   = rem >> 2;
        int xg  = rem & 3;
        float wv[25];
#pragma unroll
        for (int j = 0; j < 25; ++j) wv[j] = w1s[oc * 25 + j];
        float acc[7][4];
#pragma unroll
        for (int p = 0; p < 7; ++p)
#pragma unroll
            for (int q = 0; q < 4; ++q) acc[p][q] = 0.f;
#pragma unroll
        for (int r = 0; r < 6; ++r) {
            float row[18];
            const float* src = &xs[(2 * y + r) * 62 + 14 * xg];
#pragma unroll
            for (int k = 0; k < 9; ++k) {
                float2 v = *(const float2*)&src[2 * k];
                row[2 * k] = v.x; row[2 * k + 1] = v.y;
            }
#pragma unroll
            for (int p = 0; p < 7; ++p)
#pragma unroll
                for (int s = 0; s < 5; ++s) {
                    float x0 = row[2 * p + s], x1 = row[2 * p + 1 + s];
                    if (r < 5) {
                        float w = wv[r * 5 + s];
                        acc[p][0] += x0 * w; acc[p][1] += x1 * w;
                    }
                    if (r >= 1) {
                        float w = wv[(r - 1) * 5 + s];
                        acc[p][2] += x0 * w; acc[p][3] += x1 * w;
                    }
                }
        }
        float bias = b1[oc];
#pragma unroll
        for (int p = 0; p < 7; ++p)
            h1s[oc * 480 + y * 30 + 7 * xg + p] =
                bias + fmaxf(fmaxf(acc[p][0], acc[p][1]),
                             fmaxf(acc[p][2], acc[p][3]));
    }
    __syncthreads();

    // ---- conv2 + pool: 240 active threads = ocg(10, 5 oc) x ph(6) x pwg(4, 3 pw)
    const int ocg = t / 24;          // 0..9 (t<240)
    const int pg  = t % 24;
    const int ph  = pg >> 2;
    const int pwg = pg & 3;
    const bool active = (t < 240);

    float acc[3][5][4];
#pragma unroll
    for (int pi = 0; pi < 3; ++pi)
#pragma unroll
        for (int j = 0; j < 5; ++j)
#pragma unroll
            for (int q = 0; q < 4; ++q) acc[pi][j][q] = 0.f;

    // stage weights for ic=0 into buffer 0  (w2s[buf][oc*28 + k], k<25)
    for (int s = t; s < 1250; s += 256) {
        int oc = s / 25, k = s - 25 * oc;
        w2s[oc * 28 + k] = w2[oc * 500 + k];
    }
    __syncthreads();

#pragma unroll 1
    for (int ic = 0; ic < 20; ++ic) {
        // stage next ic's weights into the other buffer
        if (ic + 1 < 20) {
            int nb = (ic + 1) & 1;
            for (int s = t; s < 1250; s += 256) {
                int oc = s / 25, k = s - 25 * oc;
                w2s[nb * 1400 + oc * 28 + k] = w2[oc * 500 + (ic + 1) * 25 + k];
            }
        }
        if (active) {
            const float* wb = &w2s[(ic & 1) * 1400];
            float win[6][10];
#pragma unroll
            for (int r = 0; r < 6; ++r) {
                const float* src = &h1s[ic * 480 + (2 * ph + r) * 30 + 6 * pwg];
#pragma unroll
                for (int k = 0; k < 5; ++k) {
                    float2 v = *(const float2*)&src[2 * k];
                    win[r][2 * k] = v.x; win[r][2 * k + 1] = v.y;
                }
            }
#pragma unroll
            for (int j = 0; j < 5; ++j) {
                int oc = ocg * 5 + j;
                float wv[25];
                const float* wp = &wb[oc * 28];
#pragma unroll
                for (int k4 = 0; k4 < 6; ++k4) {
                    float4 v = *(const float4*)&wp[4 * k4];
                    wv[4 * k4] = v.x; wv[4 * k4 + 1] = v.y;
                    wv[4 * k4 + 2] = v.z; wv[4 * k4 + 3] = v.w;
                }
                wv[24] = wp[24];
#pragma unroll
                for (int pi = 0; pi < 3; ++pi)
#pragma unroll
                    for (int r = 0; r < 5; ++r)
#pragma unroll
                        for (int s = 0; s < 5; ++s) {
                            float w  = wv[r * 5 + s];
                            float x0 = win[r][2 * pi + s];
                            float x1 = win[r][2 * pi + 1 + s];
                            float x2 = win[r + 1][2 * pi + s];
                            float x3 = win[r + 1][2 * pi + 1 + s];
                            acc[pi][j][0] += x0 * w;
                            acc[pi][j][1] += x1 * w;
                            acc[pi][j][2] += x2 * w;
                            acc[pi][j][3] += x3 * w;
                        }
            }
        }
        __syncthreads();
    }

    // ---- write pooled conv2 result via LDS (reuse h1s) for coalesced store
    float* hs2 = h1s;  // 3600 floats
    if (active) {
#pragma unroll
        for (int j = 0; j < 5; ++j) {
            int oc = ocg * 5 + j;
            float bias = b2[oc];
#pragma unroll
            for (int pi = 0; pi < 3; ++pi) {
                int pw = 3 * pwg + pi;
                float v = bias + fmaxf(fmaxf(acc[pi][j][0], acc[pi][j][1]),
                                       fmaxf(acc[pi][j][2], acc[pi][j][3]));
                hs2[oc * 72 + ph * 12 + pw] = v;
            }
        }
    }
    __syncthreads();
    float* ho = h_out + (size_t)b * 3600;
    for (int i = t; i < 900; i += 256)
        *(float4*)&ho[4 * i] = *(const float4*)&hs2[4 * i];
}

// ---------- Kernel 2: pcaps conv(pad2) + squash + priors -------------------
// h:[B,3600] pcw:[16,50,5,5] pcb:[16] rw:[2,288,4,1] -> priors:[2,B,288]
// units(240) = icq(5, 10 ic each) x ocg(8, 2 oc each) x y(6); 12 cols per unit
__global__ __launch_bounds__(256, 2) void k_pcaps(
    const float* __restrict__ h, const float* __restrict__ pcw,
    const float* __restrict__ pcb, const float* __restrict__ rw,
    float* __restrict__ priors)
{
    __shared__ __align__(16) float hs[3600];
    __shared__ __align__(16) float psum[5 * 1152];
    const int t = threadIdx.x;
    const int b = blockIdx.x;
    {
        const float* hb = h + (size_t)b * 3600;
        for (int i = t; i < 900; i += 256)
            *(float4*)&hs[4 * i] = *(const float4*)&hb[4 * i];
    }
    __syncthreads();

    if (t < 240) {
        const int icq = t / 48;       // 0..4
        const int r48 = t % 48;
        const int ocg = r48 / 6;      // 0..7
        const int y   = r48 % 6;
        const int oc0 = 2 * ocg, oc1 = 2 * ocg + 1;
        float a0[12], a1[12];
#pragma unroll
        for (int xx = 0; xx < 12; ++xx) { a0[xx] = 0.f; a1[xx] = 0.f; }
#pragma unroll 1
        for (int ii = 0; ii < 10; ++ii) {
            int ic = icq * 10 + ii;
            float wv0[25], wv1[25];
            const float* p0 = pcw + (oc0 * 50 + ic) * 25;
            const float* p1 = pcw + (oc1 * 50 + ic) * 25;
#pragma unroll
            for (int j = 0; j < 25; ++j) { wv0[j] = p0[j]; wv1[j] = p1[j]; }
#pragma unroll
            for (int r = 0; r < 5; ++r) {
                int ry = y + r - 2;
                if ((unsigned)ry < 6u) {
                    const float* rowp = &hs[ic * 72 + ry * 12];
                    float row[12];
#pragma unroll
                    for (int k = 0; k < 3; ++k) {
                        float4 v = *(const float4*)&rowp[4 * k];
                        row[4 * k] = v.x; row[4 * k + 1] = v.y;
                        row[4 * k + 2] = v.z; row[4 * k + 3] = v.w;
                    }
#pragma unroll
                    for (int xx = 0; xx < 12; ++xx)
#pragma unroll
                        for (int s = 0; s < 5; ++s) {
                            int xi = xx + s - 2;
                            if (xi >= 0 && xi < 12) {
                                float xv = row[xi];
                                a0[xx] += xv * wv0[r * 5 + s];
                                a1[xx] += xv * wv1[r * 5 + s];
                            }
                        }
                }
            }
        }
        float* q0 = &psum[(icq * 16 + oc0) * 72 + y * 12];
        float* q1 = &psum[(icq * 16 + oc1) * 72 + y * 12];
#pragma unroll
        for (int k = 0; k < 3; ++k) {
            *(float4*)&q0[4 * k] = make_float4(a0[4*k], a0[4*k+1], a0[4*k+2], a0[4*k+3]);
            *(float4*)&q1[4 * k] = make_float4(a1[4*k], a1[4*k+1], a1[4*k+2], a1[4*k+3]);
        }
    }
    __syncthreads();

    // reduce 5 partials + bias -> psum[0..1152)
    for (int i = t; i < 1152; i += 256) {
        float s = psum[i] + psum[1152 + i] + psum[2 * 1152 + i]
                + psum[3 * 1152 + i] + psum[4 * 1152 + i] + pcb[i / 72];
        psum[i] = s;
    }
    __syncthreads();

    // squash over capsule dim + priors
    for (int r = t; r < 288; r += 256) {
        int sub = r / 72;
        int pos = r - sub * 72;
        float u0 = psum[(0 * 4 + sub) * 72 + pos];
        float u1 = psum[(1 * 4 + sub) * 72 + pos];
        float u2 = psum[(2 * 4 + sub) * 72 + pos];
        float u3 = psum[(3 * 4 + sub) * 72 + pos];
        float n2 = u0 * u0 + u1 * u1 + u2 * u2 + u3 * u3;
        float scale = (n2 / (1.0f + n2)) * rsqrtf(n2);
        u0 *= scale; u1 *= scale; u2 *= scale; u3 *= scale;
#pragma unroll
        for (int k = 0; k < 2; ++k) {
            const float* w = &rw[(k * 288 + r) * 4];
            priors[(k * BATCH + b) * 288 + r] =
                u0 * w[0] + u1 * w[1] + u2 * w[2] + u3 * w[3];
        }
    }
}

// ---------- Kernel 3: dynamic routing (3 iters), one wave per (k,b) --------
__global__ __launch_bounds__(256) void k_route(
    const float* __restrict__ priors, float* __restrict__ c)
{
    int wg   = blockIdx.x * 4 + (threadIdx.x >> 6);
    int lane = threadIdx.x & 63;
    int b = wg >> 1, k = wg & 1;
    const float* pr = priors + (k * BATCH + b) * 288;
    float p[5];
    bool  val[5];
#pragma unroll
    for (int j = 0; j < 5; ++j) {
        int r  = j * 64 + lane;
        val[j] = r < 288;
        p[j]   = val[j] ? pr[r] : 0.0f;
    }
    float tot = wave_sum(p[0] + p[1] + p[2] + p[3] + p[4]);
    float s = tot * (1.0f / 288.0f);
    float a = s * fabsf(s) / (1.0f + s * s);
#pragma unroll
    for (int it = 0; it < 2; ++it) {
        float l[5];
        float lm = -INFINITY;
#pragma unroll
        for (int j = 0; j < 5; ++j) {
            l[j] = val[j] ? p[j] * a : -INFINITY;
            lm   = fmaxf(lm, l[j]);
        }
        lm = wave_max(lm);
        float se = 0.f, sp = 0.f;
#pragma unroll
        for (int j = 0; j < 5; ++j) {
            float e = val[j] ? expf(l[j] - lm) : 0.f;
            se += e;
            sp += e * p[j];
        }
        se = wave_sum(se);
        sp = wave_sum(sp);
        float sv = sp / se;
        float v  = sv * fabsf(sv) / (1.0f + sv * sv);
        if (it == 0) a += v;
        else if (lane == 0) c[b * 2 + k] = v;
    }
}

// ---------- Kernel 4: fc1 GEMM  [2048,3600]x[500,3602]^T + caps cols -------
__global__ __launch_bounds__(256) void k_fc1(
    const float* __restrict__ h, const float* __restrict__ cc,
    const float* __restrict__ w, const float* __restrict__ bias,
    float* __restrict__ f1)
{
    __shared__ __align__(16) float As[16][64];
    __shared__ __align__(16) float Bs[16][64];
    const int t  = threadIdx.x;
    const int m0 = blockIdx.x * 64;
    const int n0 = blockIdx.y * 64;
    const int tx = t & 15, ty = t >> 4;
    const int lm = t >> 2;
    const int lk = (t & 3) * 4;
    float acc[4][4] = {};
    for (int k0 = 0; k0 < 3600; k0 += 16) {
        float4 av = *(const float4*)&h[(size_t)(m0 + lm) * 3600 + k0 + lk];
        int n = n0 + lm;
        float4 bv = make_float4(0.f, 0.f, 0.f, 0.f);
        if (n < 500) {
            const float* wp = &w[(size_t)n * 3602 + k0 + lk];
            float2 b0 = *(const float2*)wp;
            float2 b1 = *(const float2*)(wp + 2);
            bv = make_float4(b0.x, b0.y, b1.x, b1.y);
        }
        __syncthreads();
        As[lk + 0][lm] = av.x; As[lk + 1][lm] = av.y;
        As[lk + 2][lm] = av.z; As[lk + 3][lm] = av.w;
        Bs[lk + 0][lm] = bv.x; Bs[lk + 1][lm] = bv.y;
        Bs[lk + 2][lm] = bv.z; Bs[lk + 3][lm] = bv.w;
        __syncthreads();
#pragma unroll
        for (int kk = 0; kk < 16; ++kk) {
            float4 a4 = *(const float4*)&As[kk][ty * 4];
            float4 b4 = *(const float4*)&Bs[kk][tx * 4];
            float a[4]  = {a4.x, a4.y, a4.z, a4.w};
            float bb[4] = {b4.x, b4.y, b4.z, b4.w};
#pragma unroll
            for (int i2 = 0; i2 < 4; ++i2)
#pragma unroll
                for (int j2 = 0; j2 < 4; ++j2)
                    acc[i2][j2] += a[i2] * bb[j2];
        }
    }
#pragma unroll
    for (int i2 = 0; i2 < 4; ++i2) {
        int m = m0 + ty * 4 + i2;
        float c0 = cc[m * 2 + 0], c1 = cc[m * 2 + 1];
#pragma unroll
        for (int j2 = 0; j2 < 4; ++j2) {
            int n = n0 + tx * 4 + j2;
            if (n < 500) {
                float v = acc[i2][j2] + bias[n]
                        + c0 * w[(size_t)n * 3602 + 3600]
                        + c1 * w[(size_t)n * 3602 + 3601];
                f1[(size_t)m * 500 + n] = fmaxf(v, 0.0f);
            }
        }
    }
}

// ---------- Kernel 5: fc2, one wave per (b,j) ------------------------------
__global__ __launch_bounds__(256) void k_fc2(
    const float* __restrict__ f1, const float* __restrict__ y,
    const float* __restrict__ w, const float* __restrict__ bias,
    float* __restrict__ out)
{
    int wg   = blockIdx.x * 4 + (threadIdx.x >> 6);
    int lane = threadIdx.x & 63;
    int b = wg >> 1, j = wg & 1;
    const float* wj = w + j * 502;
    float acc = 0.f;
    for (int k = lane; k < 500; k += 64) acc += f1[(size_t)b * 500 + k] * wj[k];
    if (lane < 2) acc += y[b * 2 + lane] * wj[500 + lane];
    acc = wave_sum(acc);
    if (lane == 0) out[b * 2 + j] = acc + bias[j];
}

// ---------------------------------------------------------------------------
extern "C" void kernel_launch(void* const* d_in, const int* in_sizes, int n_in,
                              void* d_out, int out_size, void* d_ws, size_t ws_size,
                              hipStream_t stream) {
    const float* x    = (const float*)d_in[0];
    const float* y    = (const float*)d_in[1];
    const float* c1w  = (const float*)d_in[2];
    const float* c1b  = (const float*)d_in[3];
    const float* c2w  = (const float*)d_in[4];
    const float* c2b  = (const float*)d_in[5];
    const float* pcw  = (const float*)d_in[6];
    const float* pcb  = (const float*)d_in[7];
    const float* rw   = (const float*)d_in[8];
    const float* f1w  = (const float*)d_in[9];
    const float* f1b  = (const float*)d_in[10];
    const float* f2w  = (const float*)d_in[11];
    const float* f2b  = (const float*)d_in[12];
    float* out = (float*)d_out;

    float* ws     = (float*)d_ws;
    float* h      = ws;                        // 2048*3600
    float* priors = h + (size_t)BATCH * 3600;  // 2*2048*288
    float* cbuf   = priors + 2 * BATCH * 288;  // 4096
    float* f1     = cbuf + BATCH * 2;          // 2048*500

    k_convs<<<BATCH, 256, 0, stream>>>(x, c1w, c1b, c2w, c2b, h);
    k_pcaps<<<BATCH, 256, 0, stream>>>(h, pcw, pcb, rw, priors);
    k_route<<<BATCH * 2 / 4, 256, 0, stream>>>(priors, cbuf);
    dim3 g4(32, 8);
    k_fc1<<<g4, 256, 0, stream>>>(h, cbuf, f1w, f1b, f1);
    k_fc2<<<BATCH * 2 / 4, 256, 0, stream>>>(f1, y, f2w, f2b, out);
}

// Round 3
// 621.309 us; speedup vs baseline: 2.7400x; 1.3752x over previous
//
#include <hip/hip_runtime.h>
#include <math.h>

// ---------------------------------------------------------------------------
// Model: conv1(5x5,20)+pool2 -> conv2(5x5,50)+pool2 -> pcaps(5x5 pad2,16)
//        -> squash -> priors -> dynamic routing(3) -> fc1(relu) -> fc2
// B=2048. conv2 via bf16 MFMA (16x16x32); rest fp32 vector.
// ---------------------------------------------------------------------------

#define BATCH 2048

typedef __attribute__((ext_vector_type(8))) short short8;
typedef __attribute__((ext_vector_type(4))) float floatx4;

__device__ inline float wave_sum(float v) {
#pragma unroll
    for (int off = 32; off >= 1; off >>= 1) v += __shfl_xor(v, off);
    return v;
}
__device__ inline float wave_max(float v) {
#pragma unroll
    for (int off = 32; off >= 1; off >>= 1) v = fmaxf(v, __shfl_xor(v, off));
    return v;
}
__device__ inline unsigned short f2bf(float f) {  // RNE fp32->bf16 (finite)
    unsigned int u = __float_as_uint(f);
    unsigned int r = (u + 0x7FFFu + ((u >> 16) & 1u)) >> 16;
    return (unsigned short)r;
}

// ---------- Kernel 1: conv1+pool2 (fp32) + conv2+pool2 (bf16 MFMA) ---------
// x:[B,1,36,60] w1:[20,1,5,5] b1:[20] w2:[50,20,5,5] b2:[50]
// h_out:[B,3600]  (oc*72 + ph*12 + pw)
//
// conv2 as GEMM: M=288 pre-pool positions (Z-ordered so each pool 2x2 quad
// = 4 consecutive m = one lane's 4 C-regs), N=50 oc (pad 64), K=20 ic
// (pad 32), looped over 25 (r,s) taps.
// LDS: h1t[y16][x28][ic40] bf16 (80B pitch -> aligned b128 A-frags),
//      sbuf = union{ conv1: xs[36*62]+w1s[500] | conv2: w2b[5][64][32] bf16 }.
__global__ __launch_bounds__(256, 2) void k_convs(
    const float* __restrict__ x, const float* __restrict__ w1,
    const float* __restrict__ b1, const float* __restrict__ w2,
    const float* __restrict__ b2, float* __restrict__ h_out)
{
    __shared__ __align__(16) unsigned short h1t[17920];  // 16*28*40, 35840 B
    __shared__ __align__(16) float sbuf[5120];           // 20480 B
    float* xs  = sbuf;          // [36][62]
    float* w1s = sbuf + 2232;   // [500]

    const int t = threadIdx.x;
    const int b = blockIdx.x;

    // ---- zero h1t (ic pad must be 0), stage x (rows 60->62) and w1 ----
    for (int i = t; i < 8960; i += 256) ((unsigned int*)h1t)[i] = 0u;
    const float* xb = x + b * 2160;
    for (int i = t; i < 2160; i += 256) {
        int r = i / 60, c = i - 60 * r;
        xs[r * 62 + c] = xb[i];
    }
    for (int i = t; i < 500; i += 256) w1s[i] = w1[i];
    __syncthreads();

    // ---- conv1 + pool -> h1t[y][x][oc] bf16; units = y(16) x xg(4) x oc(20)
    // (oc fastest across lanes -> 2B-consecutive LDS writes, conflict-free)
#pragma unroll 1
    for (int u = t; u < 1280; u += 256) {
        int oc = u % 20;
        int g  = u / 20;
        int xg = g & 3;
        int y  = g >> 2;
        float wv[25];
#pragma unroll
        for (int j = 0; j < 25; ++j) wv[j] = w1s[oc * 25 + j];
        float acc[7][4];
#pragma unroll
        for (int p = 0; p < 7; ++p)
#pragma unroll
            for (int qq = 0; qq < 4; ++qq) acc[p][qq] = 0.f;
#pragma unroll
        for (int r = 0; r < 6; ++r) {
            float row[18];
            const float* src = &xs[(2 * y + r) * 62 + 14 * xg];
#pragma unroll
            for (int k = 0; k < 9; ++k) {
                float2 v = *(const float2*)&src[2 * k];
                row[2 * k] = v.x; row[2 * k + 1] = v.y;
            }
#pragma unroll
            for (int p = 0; p < 7; ++p)
#pragma unroll
                for (int s = 0; s < 5; ++s) {
                    float x0 = row[2 * p + s], x1 = row[2 * p + 1 + s];
                    if (r < 5) {
                        float w = wv[r * 5 + s];
                        acc[p][0] += x0 * w; acc[p][1] += x1 * w;
                    }
                    if (r >= 1) {
                        float w = wv[(r - 1) * 5 + s];
                        acc[p][2] += x0 * w; acc[p][3] += x1 * w;
                    }
                }
        }
        float bias = b1[oc];
#pragma unroll
        for (int p = 0; p < 7; ++p) {
            float v = bias + fmaxf(fmaxf(acc[p][0], acc[p][1]),
                                   fmaxf(acc[p][2], acc[p][3]));
            h1t[(y * 28 + 7 * xg + p) * 40 + oc] = f2bf(v);
        }
    }

    // ---- conv2 via MFMA ----
    const int lane = t & 63, w = t >> 6;
    const int r16  = lane & 15;       // C col / A row within tile
    const int q    = lane >> 4;       // quad
    // A-frag base index per m-tile (wave w owns mt = w, w+4, ..., <18)
    int abase[5];
#pragma unroll
    for (int i = 0; i < 5; ++i) {
        int mt = w + 4 * i;
        if (mt < 18) {
            int m  = mt * 16 + r16;
            int pq = m >> 2, sub = m & 3;
            int py = pq / 12, px = pq - py * 12;
            int yy = py * 2 + (sub >> 1);
            int xx = px * 2 + (sub & 1);
            abase[i] = (yy * 28 + xx) * 40 + q * 8;
        } else abase[i] = 0;
    }
    floatx4 acc2[5][4] = {};  // [m-tile][n-tile], f32x4 each
    unsigned short* w2b = (unsigned short*)sbuf;  // [s5][oc64][ic32]
    const int bbase = r16 * 32 + q * 8;

#pragma unroll 1
    for (int r = 0; r < 5; ++r) {
        __syncthreads();  // previous iter's B reads done (also conv1 phase at r=0)
        // stage w2b[s][oc][ic] = bf16(w2[oc][ic][r][s]), ic 20..31 zero
        for (int i = t; i < 8000; i += 256) {
            int oc = i / 160, rem = i - oc * 160;
            int s  = rem >> 5, ic = rem & 31;
            float v = (ic < 20) ? w2[oc * 500 + ic * 25 + r * 5 + s] : 0.f;
            w2b[(s * 64 + oc) * 32 + ic] = f2bf(v);
        }
        __syncthreads();
        const int aoff_r = r * 1120;  // r*28*40
#pragma unroll
        for (int s = 0; s < 5; ++s) {
            short8 bf[4];
#pragma unroll
            for (int nt = 0; nt < 4; ++nt)
                bf[nt] = *(const short8*)&w2b[s * 2048 + nt * 512 + bbase];
#pragma unroll
            for (int i = 0; i < 5; ++i) {
                int mt = w + 4 * i;
                if (mt < 18) {
                    short8 af = *(const short8*)&h1t[abase[i] + aoff_r + s * 40];
#pragma unroll
                    for (int nt = 0; nt < 4; ++nt)
                        acc2[i][nt] = __builtin_amdgcn_mfma_f32_16x16x32_bf16(
                            af, bf[nt], acc2[i][nt], 0, 0, 0);
                }
            }
        }
    }
    __syncthreads();  // all A-reads of h1t done; reuse h1t as f32 out-stage

    // ---- pool (lane-local: Z-order puts the 2x2 quad in this lane's 4 regs)
    float* hs2 = (float*)h1t;  // 3600 f32
#pragma unroll
    for (int i = 0; i < 5; ++i) {
        int mt = w + 4 * i;
        if (mt < 18) {
            int pq = mt * 4 + q;   // = py*12 + px
#pragma unroll
            for (int nt = 0; nt < 4; ++nt) {
                int oc = nt * 16 + r16;
                if (oc < 50) {
                    floatx4 a = acc2[i][nt];
                    float v = fmaxf(fmaxf(a[0], a[1]), fmaxf(a[2], a[3])) + b2[oc];
                    hs2[oc * 72 + pq] = v;
                }
            }
        }
    }
    __syncthreads();
    float* ho = h_out + (size_t)b * 3600;
    for (int i = t; i < 900; i += 256)
        *(float4*)&ho[4 * i] = *(const float4*)&hs2[4 * i];
}

// ---------- Kernel 2: pcaps conv(pad2) + squash + priors -------------------
__global__ __launch_bounds__(256, 2) void k_pcaps(
    const float* __restrict__ h, const float* __restrict__ pcw,
    const float* __restrict__ pcb, const float* __restrict__ rw,
    float* __restrict__ priors)
{
    __shared__ __align__(16) float hs[3600];
    __shared__ __align__(16) float psum[5 * 1152];
    const int t = threadIdx.x;
    const int b = blockIdx.x;
    {
        const float* hb = h + (size_t)b * 3600;
        for (int i = t; i < 900; i += 256)
            *(float4*)&hs[4 * i] = *(const float4*)&hb[4 * i];
    }
    __syncthreads();

    if (t < 240) {
        const int icq = t / 48;
        const int r48 = t % 48;
        const int ocg = r48 / 6;
        const int y   = r48 % 6;
        const int oc0 = 2 * ocg, oc1 = 2 * ocg + 1;
        float a0[12], a1[12];
#pragma unroll
        for (int xx = 0; xx < 12; ++xx) { a0[xx] = 0.f; a1[xx] = 0.f; }
#pragma unroll 1
        for (int ii = 0; ii < 10; ++ii) {
            int ic = icq * 10 + ii;
            float wv0[25], wv1[25];
            const float* p0 = pcw + (oc0 * 50 + ic) * 25;
            const float* p1 = pcw + (oc1 * 50 + ic) * 25;
#pragma unroll
            for (int j = 0; j < 25; ++j) { wv0[j] = p0[j]; wv1[j] = p1[j]; }
#pragma unroll
            for (int r = 0; r < 5; ++r) {
                int ry = y + r - 2;
                if ((unsigned)ry < 6u) {
                    const float* rowp = &hs[ic * 72 + ry * 12];
                    float row[12];
#pragma unroll
                    for (int k = 0; k < 3; ++k) {
                        float4 v = *(const float4*)&rowp[4 * k];
                        row[4 * k] = v.x; row[4 * k + 1] = v.y;
                        row[4 * k + 2] = v.z; row[4 * k + 3] = v.w;
                    }
#pragma unroll
                    for (int xx = 0; xx < 12; ++xx)
#pragma unroll
                        for (int s = 0; s < 5; ++s) {
                            int xi = xx + s - 2;
                            if (xi >= 0 && xi < 12) {
                                float xv = row[xi];
                                a0[xx] += xv * wv0[r * 5 + s];
                                a1[xx] += xv * wv1[r * 5 + s];
                            }
                        }
                }
            }
        }
        float* q0 = &psum[(icq * 16 + oc0) * 72 + y * 12];
        float* q1 = &psum[(icq * 16 + oc1) * 72 + y * 12];
#pragma unroll
        for (int k = 0; k < 3; ++k) {
            *(float4*)&q0[4 * k] = make_float4(a0[4*k], a0[4*k+1], a0[4*k+2], a0[4*k+3]);
            *(float4*)&q1[4 * k] = make_float4(a1[4*k], a1[4*k+1], a1[4*k+2], a1[4*k+3]);
        }
    }
    __syncthreads();

    for (int i = t; i < 1152; i += 256) {
        float s = psum[i] + psum[1152 + i] + psum[2 * 1152 + i]
                + psum[3 * 1152 + i] + psum[4 * 1152 + i] + pcb[i / 72];
        psum[i] = s;
    }
    __syncthreads();

    for (int r = t; r < 288; r += 256) {
        int sub = r / 72;
        int pos = r - sub * 72;
        float u0 = psum[(0 * 4 + sub) * 72 + pos];
        float u1 = psum[(1 * 4 + sub) * 72 + pos];
        float u2 = psum[(2 * 4 + sub) * 72 + pos];
        float u3 = psum[(3 * 4 + sub) * 72 + pos];
        float n2 = u0 * u0 + u1 * u1 + u2 * u2 + u3 * u3;
        float scale = (n2 / (1.0f + n2)) * rsqrtf(n2);
        u0 *= scale; u1 *= scale; u2 *= scale; u3 *= scale;
#pragma unroll
        for (int k = 0; k < 2; ++k) {
            const float* w = &rw[(k * 288 + r) * 4];
            priors[(k * BATCH + b) * 288 + r] =
                u0 * w[0] + u1 * w[1] + u2 * w[2] + u3 * w[3];
        }
    }
}

// ---------- Kernel 3: dynamic routing (3 iters), one wave per (k,b) --------
__global__ __launch_bounds__(256) void k_route(
    const float* __restrict__ priors, float* __restrict__ c)
{
    int wg   = blockIdx.x * 4 + (threadIdx.x >> 6);
    int lane = threadIdx.x & 63;
    int b = wg >> 1, k = wg & 1;
    const float* pr = priors + (k * BATCH + b) * 288;
    float p[5];
    bool  val[5];
#pragma unroll
    for (int j = 0; j < 5; ++j) {
        int r  = j * 64 + lane;
        val[j] = r < 288;
        p[j]   = val[j] ? pr[r] : 0.0f;
    }
    float tot = wave_sum(p[0] + p[1] + p[2] + p[3] + p[4]);
    float s = tot * (1.0f / 288.0f);
    float a = s * fabsf(s) / (1.0f + s * s);
#pragma unroll
    for (int it = 0; it < 2; ++it) {
        float l[5];
        float lm = -INFINITY;
#pragma unroll
        for (int j = 0; j < 5; ++j) {
            l[j] = val[j] ? p[j] * a : -INFINITY;
            lm   = fmaxf(lm, l[j]);
        }
        lm = wave_max(lm);
        float se = 0.f, sp = 0.f;
#pragma unroll
        for (int j = 0; j < 5; ++j) {
            float e = val[j] ? expf(l[j] - lm) : 0.f;
            se += e;
            sp += e * p[j];
        }
        se = wave_sum(se);
        sp = wave_sum(sp);
        float sv = sp / se;
        float v  = sv * fabsf(sv) / (1.0f + sv * sv);
        if (it == 0) a += v;
        else if (lane == 0) c[b * 2 + k] = v;
    }
}

// ---------- Kernel 4: fc1 GEMM  [2048,3600]x[500,3602]^T + caps cols -------
__global__ __launch_bounds__(256) void k_fc1(
    const float* __restrict__ h, const float* __restrict__ cc,
    const float* __restrict__ w, const float* __restrict__ bias,
    float* __restrict__ f1)
{
    __shared__ __align__(16) float As[16][64];
    __shared__ __align__(16) float Bs[16][64];
    const int t  = threadIdx.x;
    const int m0 = blockIdx.x * 64;
    const int n0 = blockIdx.y * 64;
    const int tx = t & 15, ty = t >> 4;
    const int lm = t >> 2;
    const int lk = (t & 3) * 4;
    float acc[4][4] = {};
    for (int k0 = 0; k0 < 3600; k0 += 16) {
        float4 av = *(const float4*)&h[(size_t)(m0 + lm) * 3600 + k0 + lk];
        int n = n0 + lm;
        float4 bv = make_float4(0.f, 0.f, 0.f, 0.f);
        if (n < 500) {
            const float* wp = &w[(size_t)n * 3602 + k0 + lk];
            float2 b0 = *(const float2*)wp;
            float2 b1 = *(const float2*)(wp + 2);
            bv = make_float4(b0.x, b0.y, b1.x, b1.y);
        }
        __syncthreads();
        As[lk + 0][lm] = av.x; As[lk + 1][lm] = av.y;
        As[lk + 2][lm] = av.z; As[lk + 3][lm] = av.w;
        Bs[lk + 0][lm] = bv.x; Bs[lk + 1][lm] = bv.y;
        Bs[lk + 2][lm] = bv.z; Bs[lk + 3][lm] = bv.w;
        __syncthreads();
#pragma unroll
        for (int kk = 0; kk < 16; ++kk) {
            float4 a4 = *(const float4*)&As[kk][ty * 4];
            float4 b4 = *(const float4*)&Bs[kk][tx * 4];
            float a[4]  = {a4.x, a4.y, a4.z, a4.w};
            float bb[4] = {b4.x, b4.y, b4.z, b4.w};
#pragma unroll
            for (int i2 = 0; i2 < 4; ++i2)
#pragma unroll
                for (int j2 = 0; j2 < 4; ++j2)
                    acc[i2][j2] += a[i2] * bb[j2];
        }
    }
#pragma unroll
    for (int i2 = 0; i2 < 4; ++i2) {
        int m = m0 + ty * 4 + i2;
        float c0 = cc[m * 2 + 0], c1 = cc[m * 2 + 1];
#pragma unroll
        for (int j2 = 0; j2 < 4; ++j2) {
            int n = n0 + tx * 4 + j2;
            if (n < 500) {
                float v = acc[i2][j2] + bias[n]
                        + c0 * w[(size_t)n * 3602 + 3600]
                        + c1 * w[(size_t)n * 3602 + 3601];
                f1[(size_t)m * 500 + n] = fmaxf(v, 0.0f);
            }
        }
    }
}

// ---------- Kernel 5: fc2, one wave per (b,j) ------------------------------
__global__ __launch_bounds__(256) void k_fc2(
    const float* __restrict__ f1, const float* __restrict__ y,
    const float* __restrict__ w, const float* __restrict__ bias,
    float* __restrict__ out)
{
    int wg   = blockIdx.x * 4 + (threadIdx.x >> 6);
    int lane = threadIdx.x & 63;
    int b = wg >> 1, j = wg & 1;
    const float* wj = w + j * 502;
    float acc = 0.f;
    for (int k = lane; k < 500; k += 64) acc += f1[(size_t)b * 500 + k] * wj[k];
    if (lane < 2) acc += y[b * 2 + lane] * wj[500 + lane];
    acc = wave_sum(acc);
    if (lane == 0) out[b * 2 + j] = acc + bias[j];
}

// ---------------------------------------------------------------------------
extern "C" void kernel_launch(void* const* d_in, const int* in_sizes, int n_in,
                              void* d_out, int out_size, void* d_ws, size_t ws_size,
                              hipStream_t stream) {
    const float* x    = (const float*)d_in[0];
    const float* y    = (const float*)d_in[1];
    const float* c1w  = (const float*)d_in[2];
    const float* c1b  = (const float*)d_in[3];
    const float* c2w  = (const float*)d_in[4];
    const float* c2b  = (const float*)d_in[5];
    const float* pcw  = (const float*)d_in[6];
    const float* pcb  = (const float*)d_in[7];
    const float* rw   = (const float*)d_in[8];
    const float* f1w  = (const float*)d_in[9];
    const float* f1b  = (const float*)d_in[10];
    const float* f2w  = (const float*)d_in[11];
    const float* f2b  = (const float*)d_in[12];
    float* out = (float*)d_out;

    float* ws     = (float*)d_ws;
    float* h      = ws;                        // 2048*3600
    float* priors = h + (size_t)BATCH * 3600;  // 2*2048*288
    float* cbuf   = priors + 2 * BATCH * 288;  // 4096
    float* f1     = cbuf + BATCH * 2;          // 2048*500

    k_convs<<<BATCH, 256, 0, stream>>>(x, c1w, c1b, c2w, c2b, h);
    k_pcaps<<<BATCH, 256, 0, stream>>>(h, pcw, pcb, rw, priors);
    k_route<<<BATCH * 2 / 4, 256, 0, stream>>>(priors, cbuf);
    dim3 g4(32, 8);
    k_fc1<<<g4, 256, 0, stream>>>(h, cbuf, f1w, f1b, f1);
    k_fc2<<<BATCH * 2 / 4, 256, 0, stream>>>(f1, y, f2w, f2b, out);
}

// Round 4
// 437.994 us; speedup vs baseline: 3.8868x; 1.4185x over previous
//
#include <hip/hip_runtime.h>
#include <math.h>

// ---------------------------------------------------------------------------
// Model: conv1(5x5,20)+pool2 -> conv2(5x5,50)+pool2 -> pcaps(5x5 pad2,16)
//        -> squash -> priors -> dynamic routing(3) -> fc1(relu) -> fc2
// B=2048. conv2 + fc1 via bf16 MFMA (16x16x32); rest fp32 vector.
// h is stored bf16-only ([B][3616], zero-padded) - feeds both pcaps and fc1.
// ---------------------------------------------------------------------------

#define BATCH 2048

typedef __attribute__((ext_vector_type(8))) short short8;
typedef __attribute__((ext_vector_type(4))) float floatx4;
typedef unsigned short u16;
typedef unsigned int   u32;

__device__ inline float wave_sum(float v) {
#pragma unroll
    for (int off = 32; off >= 1; off >>= 1) v += __shfl_xor(v, off);
    return v;
}
__device__ inline float wave_max(float v) {
#pragma unroll
    for (int off = 32; off >= 1; off >>= 1) v = fmaxf(v, __shfl_xor(v, off));
    return v;
}
__device__ inline u16 f2bf(float f) {  // RNE fp32->bf16 (finite)
    u32 u = __float_as_uint(f);
    u32 r = (u + 0x7FFFu + ((u >> 16) & 1u)) >> 16;
    return (u16)r;
}

// ---------- Kernel 0: fc1 weights -> bf16 [512][3616] ----------------------
__global__ __launch_bounds__(256) void k_wconv(const float* __restrict__ fw,
                                               u16* __restrict__ w_bf) {
    int g  = blockIdx.x * 256 + threadIdx.x;  // one 8-short group (3616%8==0)
    int n  = (g * 8) / 3616;
    int k0 = (g * 8) % 3616;
    u16 v[8];
#pragma unroll
    for (int j = 0; j < 8; ++j) {
        int k = k0 + j;
        float f = (n < 500 && k < 3600) ? fw[(size_t)n * 3602 + k] : 0.f;
        v[j] = f2bf(f);
    }
    *(short8*)&w_bf[(size_t)g * 8] = *(short8*)v;
}

// ---------- Kernel 1: conv1+pool2 (fp32) + conv2+pool2 (bf16 MFMA) ---------
// x:[B,1,36,60] w1:[20,1,5,5] b1:[20] w2:[50,20,5,5] b2:[50]
// h_bf:[B][3616] bf16 (oc*72 + ph*12 + pw; 3600..3615 zero)
__global__ __launch_bounds__(256, 2) void k_convs(
    const float* __restrict__ x, const float* __restrict__ w1,
    const float* __restrict__ b1, const float* __restrict__ w2,
    const float* __restrict__ b2, u32* __restrict__ h_bf)
{
    __shared__ __align__(16) u16 h1t[17920];   // 16*28*40 bf16, 35840 B
    __shared__ __align__(16) float sbuf[5120]; // 20480 B
    float* xs  = sbuf;          // [36][62]
    float* w1s = sbuf + 2232;   // [500]

    const int t = threadIdx.x;
    const int b = blockIdx.x;

    for (int i = t; i < 8960; i += 256) ((u32*)h1t)[i] = 0u;
    const float* xb = x + b * 2160;
    for (int i = t; i < 2160; i += 256) {
        int r = i / 60, c = i - 60 * r;
        xs[r * 62 + c] = xb[i];
    }
    for (int i = t; i < 500; i += 256) w1s[i] = w1[i];
    __syncthreads();

    // conv1 + pool -> h1t[y][x][oc] bf16
#pragma unroll 1
    for (int u = t; u < 1280; u += 256) {
        int oc = u % 20;
        int g  = u / 20;
        int xg = g & 3;
        int y  = g >> 2;
        float wv[25];
#pragma unroll
        for (int j = 0; j < 25; ++j) wv[j] = w1s[oc * 25 + j];
        float acc[7][4];
#pragma unroll
        for (int p = 0; p < 7; ++p)
#pragma unroll
            for (int qq = 0; qq < 4; ++qq) acc[p][qq] = 0.f;
#pragma unroll
        for (int r = 0; r < 6; ++r) {
            float row[18];
            const float* src = &xs[(2 * y + r) * 62 + 14 * xg];
#pragma unroll
            for (int k = 0; k < 9; ++k) {
                float2 v = *(const float2*)&src[2 * k];
                row[2 * k] = v.x; row[2 * k + 1] = v.y;
            }
#pragma unroll
            for (int p = 0; p < 7; ++p)
#pragma unroll
                for (int s = 0; s < 5; ++s) {
                    float x0 = row[2 * p + s], x1 = row[2 * p + 1 + s];
                    if (r < 5) {
                        float w = wv[r * 5 + s];
                        acc[p][0] += x0 * w; acc[p][1] += x1 * w;
                    }
                    if (r >= 1) {
                        float w = wv[(r - 1) * 5 + s];
                        acc[p][2] += x0 * w; acc[p][3] += x1 * w;
                    }
                }
        }
        float bias = b1[oc];
#pragma unroll
        for (int p = 0; p < 7; ++p) {
            float v = bias + fmaxf(fmaxf(acc[p][0], acc[p][1]),
                                   fmaxf(acc[p][2], acc[p][3]));
            h1t[(y * 28 + 7 * xg + p) * 40 + oc] = f2bf(v);
        }
    }

    // conv2 via MFMA: M=288 Z-ordered pre-pool positions, N=64, K=32, 25 taps
    const int lane = t & 63, w = t >> 6;
    const int r16  = lane & 15;
    const int q    = lane >> 4;
    int abase[5];
#pragma unroll
    for (int i = 0; i < 5; ++i) {
        int mt = w + 4 * i;
        if (mt < 18) {
            int m  = mt * 16 + r16;
            int pq = m >> 2, sub = m & 3;
            int py = pq / 12, px = pq - py * 12;
            int yy = py * 2 + (sub >> 1);
            int xx = px * 2 + (sub & 1);
            abase[i] = (yy * 28 + xx) * 40 + q * 8;
        } else abase[i] = 0;
    }
    floatx4 acc2[5][4] = {};
    u16* w2b = (u16*)sbuf;  // [s5][oc64][ic32]
    const int bbase = r16 * 32 + q * 8;

#pragma unroll 1
    for (int r = 0; r < 5; ++r) {
        __syncthreads();
        for (int i = t; i < 8000; i += 256) {
            int oc = i / 160, rem = i - oc * 160;
            int s  = rem >> 5, ic = rem & 31;
            float v = (ic < 20) ? w2[oc * 500 + ic * 25 + r * 5 + s] : 0.f;
            w2b[(s * 64 + oc) * 32 + ic] = f2bf(v);
        }
        __syncthreads();
        const int aoff_r = r * 1120;
#pragma unroll
        for (int s = 0; s < 5; ++s) {
            short8 bf[4];
#pragma unroll
            for (int nt = 0; nt < 4; ++nt)
                bf[nt] = *(const short8*)&w2b[s * 2048 + nt * 512 + bbase];
#pragma unroll
            for (int i = 0; i < 5; ++i) {
                int mt = w + 4 * i;
                if (mt < 18) {
                    short8 af = *(const short8*)&h1t[abase[i] + aoff_r + s * 40];
#pragma unroll
                    for (int nt = 0; nt < 4; ++nt)
                        acc2[i][nt] = __builtin_amdgcn_mfma_f32_16x16x32_bf16(
                            af, bf[nt], acc2[i][nt], 0, 0, 0);
                }
            }
        }
    }
    __syncthreads();

    // pool (lane-local quad) -> f32 stage in LDS
    float* hs2 = (float*)h1t;  // 3600 f32
#pragma unroll
    for (int i = 0; i < 5; ++i) {
        int mt = w + 4 * i;
        if (mt < 18) {
            int pq = mt * 4 + q;
#pragma unroll
            for (int nt = 0; nt < 4; ++nt) {
                int oc = nt * 16 + r16;
                if (oc < 50) {
                    floatx4 a = acc2[i][nt];
                    float v = fmaxf(fmaxf(a[0], a[1]), fmaxf(a[2], a[3])) + b2[oc];
                    hs2[oc * 72 + pq] = v;
                }
            }
        }
    }
    __syncthreads();
    // pack to bf16 (zero tail 3600..3615)
    u32* ho = h_bf + (size_t)b * 1808;
    for (int i = t; i < 1808; i += 256) {
        int i2 = 2 * i;
        u32 lo = (i2 < 3600) ? f2bf(hs2[i2]) : 0u;
        u32 hi = (i2 + 1 < 3600) ? f2bf(hs2[i2 + 1]) : 0u;
        ho[i] = lo | (hi << 16);
    }
}

// ---------- Kernel 2: pcaps conv(pad2) + squash + priors -------------------
__global__ __launch_bounds__(256, 2) void k_pcaps(
    const u32* __restrict__ h_bf, const float* __restrict__ pcw,
    const float* __restrict__ pcb, const float* __restrict__ rw,
    float* __restrict__ priors)
{
    __shared__ __align__(16) float hs[3616];
    __shared__ __align__(16) float psum[5 * 1152];
    const int t = threadIdx.x;
    const int b = blockIdx.x;
    {
        const u32* hb = h_bf + (size_t)b * 1808;
        for (int i = t; i < 1808; i += 256) {
            u32 u = hb[i];
            hs[2 * i]     = __uint_as_float(u << 16);
            hs[2 * i + 1] = __uint_as_float(u & 0xFFFF0000u);
        }
    }
    __syncthreads();

    if (t < 240) {
        const int icq = t / 48;
        const int r48 = t % 48;
        const int ocg = r48 / 6;
        const int y   = r48 % 6;
        const int oc0 = 2 * ocg, oc1 = 2 * ocg + 1;
        float a0[12], a1[12];
#pragma unroll
        for (int xx = 0; xx < 12; ++xx) { a0[xx] = 0.f; a1[xx] = 0.f; }
#pragma unroll 1
        for (int ii = 0; ii < 10; ++ii) {
            int ic = icq * 10 + ii;
            float wv0[25], wv1[25];
            const float* p0 = pcw + (oc0 * 50 + ic) * 25;
            const float* p1 = pcw + (oc1 * 50 + ic) * 25;
#pragma unroll
            for (int j = 0; j < 25; ++j) { wv0[j] = p0[j]; wv1[j] = p1[j]; }
#pragma unroll
            for (int r = 0; r < 5; ++r) {
                int ry = y + r - 2;
                if ((unsigned)ry < 6u) {
                    const float* rowp = &hs[ic * 72 + ry * 12];
                    float row[12];
#pragma unroll
                    for (int k = 0; k < 3; ++k) {
                        float4 v = *(const float4*)&rowp[4 * k];
                        row[4 * k] = v.x; row[4 * k + 1] = v.y;
                        row[4 * k + 2] = v.z; row[4 * k + 3] = v.w;
                    }
#pragma unroll
                    for (int xx = 0; xx < 12; ++xx)
#pragma unroll
                        for (int s = 0; s < 5; ++s) {
                            int xi = xx + s - 2;
                            if (xi >= 0 && xi < 12) {
                                float xv = row[xi];
                                a0[xx] += xv * wv0[r * 5 + s];
                                a1[xx] += xv * wv1[r * 5 + s];
                            }
                        }
                }
            }
        }
        float* q0 = &psum[(icq * 16 + oc0) * 72 + y * 12];
        float* q1 = &psum[(icq * 16 + oc1) * 72 + y * 12];
#pragma unroll
        for (int k = 0; k < 3; ++k) {
            *(float4*)&q0[4 * k] = make_float4(a0[4*k], a0[4*k+1], a0[4*k+2], a0[4*k+3]);
            *(float4*)&q1[4 * k] = make_float4(a1[4*k], a1[4*k+1], a1[4*k+2], a1[4*k+3]);
        }
    }
    __syncthreads();

    for (int i = t; i < 1152; i += 256) {
        float s = psum[i] + psum[1152 + i] + psum[2 * 1152 + i]
                + psum[3 * 1152 + i] + psum[4 * 1152 + i] + pcb[i / 72];
        psum[i] = s;
    }
    __syncthreads();

    for (int r = t; r < 288; r += 256) {
        int sub = r / 72;
        int pos = r - sub * 72;
        float u0 = psum[(0 * 4 + sub) * 72 + pos];
        float u1 = psum[(1 * 4 + sub) * 72 + pos];
        float u2 = psum[(2 * 4 + sub) * 72 + pos];
        float u3 = psum[(3 * 4 + sub) * 72 + pos];
        float n2 = u0 * u0 + u1 * u1 + u2 * u2 + u3 * u3;
        float scale = (n2 / (1.0f + n2)) * rsqrtf(n2);
        u0 *= scale; u1 *= scale; u2 *= scale; u3 *= scale;
#pragma unroll
        for (int k = 0; k < 2; ++k) {
            const float* w = &rw[(k * 288 + r) * 4];
            priors[(k * BATCH + b) * 288 + r] =
                u0 * w[0] + u1 * w[1] + u2 * w[2] + u3 * w[3];
        }
    }
}

// ---------- Kernel 3: dynamic routing (3 iters), one wave per (k,b) --------
__global__ __launch_bounds__(256) void k_route(
    const float* __restrict__ priors, float* __restrict__ c)
{
    int wg   = blockIdx.x * 4 + (threadIdx.x >> 6);
    int lane = threadIdx.x & 63;
    int b = wg >> 1, k = wg & 1;
    const float* pr = priors + (k * BATCH + b) * 288;
    float p[5];
    bool  val[5];
#pragma unroll
    for (int j = 0; j < 5; ++j) {
        int r  = j * 64 + lane;
        val[j] = r < 288;
        p[j]   = val[j] ? pr[r] : 0.0f;
    }
    float tot = wave_sum(p[0] + p[1] + p[2] + p[3] + p[4]);
    float s = tot * (1.0f / 288.0f);
    float a = s * fabsf(s) / (1.0f + s * s);
#pragma unroll
    for (int it = 0; it < 2; ++it) {
        float l[5];
        float lm = -INFINITY;
#pragma unroll
        for (int j = 0; j < 5; ++j) {
            l[j] = val[j] ? p[j] * a : -INFINITY;
            lm   = fmaxf(lm, l[j]);
        }
        lm = wave_max(lm);
        float se = 0.f, sp = 0.f;
#pragma unroll
        for (int j = 0; j < 5; ++j) {
            float e = val[j] ? expf(l[j] - lm) : 0.f;
            se += e;
            sp += e * p[j];
        }
        se = wave_sum(se);
        sp = wave_sum(sp);
        float sv = sp / se;
        float v  = sv * fabsf(sv) / (1.0f + sv * sv);
        if (it == 0) a += v;
        else if (lane == 0) c[b * 2 + k] = v;
    }
}

// ---------- Kernel 4: fc1 bf16 MFMA GEMM [2048,3616]x[512,3616]^T ----------
// 64x64 tile, BK=32, register-prefetch pipeline. Epilogue: +bias +caps, relu.
__global__ __launch_bounds__(256) void k_fc1(
    const u16* __restrict__ h_bf, const u16* __restrict__ w_bf,
    const float* __restrict__ cc, const float* __restrict__ w,
    const float* __restrict__ bias, float* __restrict__ f1)
{
    __shared__ __align__(16) u16 As[64 * 40];  // pitch 40 shorts (80B)
    __shared__ __align__(16) u16 Bs[64 * 40];
    const int t  = threadIdx.x;
    const int m0 = blockIdx.x * 64;
    const int n0 = blockIdx.y * 64;
    const int row = t >> 2, c8 = (t & 3) * 8;
    const u16* ha = &h_bf[(size_t)(m0 + row) * 3616 + c8];
    const u16* wa = &w_bf[(size_t)(n0 + row) * 3616 + c8];
    short8 areg = *(const short8*)ha;
    short8 breg = *(const short8*)wa;
    const int lane = t & 63, wv = t >> 6;
    const int r16 = lane & 15, q = lane >> 4;
    const int wr = row * 40 + (t & 3) * 8;
    const int ar = (wv * 16 + r16) * 40 + q * 8;
    const int br = r16 * 40 + q * 8;
    floatx4 acc[4] = {};
#pragma unroll 1
    for (int it = 0; it < 113; ++it) {
        __syncthreads();
        *(short8*)&As[wr] = areg;
        *(short8*)&Bs[wr] = breg;
        __syncthreads();
        if (it < 112) {
            areg = *(const short8*)(ha + (it + 1) * 32);
            breg = *(const short8*)(wa + (it + 1) * 32);
        }
        short8 af = *(const short8*)&As[ar];
#pragma unroll
        for (int nt = 0; nt < 4; ++nt) {
            short8 bf = *(const short8*)&Bs[nt * 640 + br];
            acc[nt] = __builtin_amdgcn_mfma_f32_16x16x32_bf16(af, bf, acc[nt], 0, 0, 0);
        }
    }
    const int mbase = m0 + wv * 16 + q * 4;
#pragma unroll
    for (int nt = 0; nt < 4; ++nt) {
        int n = n0 + nt * 16 + r16;
        if (n < 500) {
            float bn  = bias[n];
            float wc0 = w[(size_t)n * 3602 + 3600];
            float wc1 = w[(size_t)n * 3602 + 3601];
#pragma unroll
            for (int i = 0; i < 4; ++i) {
                int m = mbase + i;
                float v = acc[nt][i] + bn + cc[m * 2] * wc0 + cc[m * 2 + 1] * wc1;
                f1[(size_t)m * 500 + n] = fmaxf(v, 0.f);
            }
        }
    }
}

// ---------- Kernel 5: fc2, one wave per (b,j) ------------------------------
__global__ __launch_bounds__(256) void k_fc2(
    const float* __restrict__ f1, const float* __restrict__ y,
    const float* __restrict__ w, const float* __restrict__ bias,
    float* __restrict__ out)
{
    int wg   = blockIdx.x * 4 + (threadIdx.x >> 6);
    int lane = threadIdx.x & 63;
    int b = wg >> 1, j = wg & 1;
    const float* wj = w + j * 502;
    float acc = 0.f;
    for (int k = lane; k < 500; k += 64) acc += f1[(size_t)b * 500 + k] * wj[k];
    if (lane < 2) acc += y[b * 2 + lane] * wj[500 + lane];
    acc = wave_sum(acc);
    if (lane == 0) out[b * 2 + j] = acc + bias[j];
}

// ---------------------------------------------------------------------------
extern "C" void kernel_launch(void* const* d_in, const int* in_sizes, int n_in,
                              void* d_out, int out_size, void* d_ws, size_t ws_size,
                              hipStream_t stream) {
    const float* x    = (const float*)d_in[0];
    const float* y    = (const float*)d_in[1];
    const float* c1w  = (const float*)d_in[2];
    const float* c1b  = (const float*)d_in[3];
    const float* c2w  = (const float*)d_in[4];
    const float* c2b  = (const float*)d_in[5];
    const float* pcw  = (const float*)d_in[6];
    const float* pcb  = (const float*)d_in[7];
    const float* rw   = (const float*)d_in[8];
    const float* f1w  = (const float*)d_in[9];
    const float* f1b  = (const float*)d_in[10];
    const float* f2w  = (const float*)d_in[11];
    const float* f2b  = (const float*)d_in[12];
    float* out = (float*)d_out;

    // workspace layout
    u32*   h_bf   = (u32*)d_ws;                           // 2048*1808 u32 = 14.8MB
    u16*   w_bf   = (u16*)(h_bf + (size_t)BATCH * 1808);  // 512*3616 u16 = 3.7MB
    float* priors = (float*)(w_bf + (size_t)512 * 3616);  // 2*2048*288
    float* cbuf   = priors + 2 * BATCH * 288;             // 4096
    float* f1     = cbuf + BATCH * 2;                     // 2048*500

    k_wconv<<<904, 256, 0, stream>>>(f1w, w_bf);
    k_convs<<<BATCH, 256, 0, stream>>>(x, c1w, c1b, c2w, c2b, h_bf);
    k_pcaps<<<BATCH, 256, 0, stream>>>(h_bf, pcw, pcb, rw, priors);
    k_route<<<BATCH * 2 / 4, 256, 0, stream>>>(priors, cbuf);
    dim3 g4(32, 8);
    k_fc1<<<g4, 256, 0, stream>>>((const u16*)h_bf, w_bf, cbuf, f1w, f1b, f1);
    k_fc2<<<BATCH * 2 / 4, 256, 0, stream>>>(f1, y, f2w, f2b, out);
}

// Round 5
// 331.313 us; speedup vs baseline: 5.1384x; 1.3220x over previous
//
#include <hip/hip_runtime.h>
#include <math.h>

// ---------------------------------------------------------------------------
// Model: conv1(5x5,20)+pool2 -> conv2(5x5,50)+pool2 -> pcaps(5x5 pad2,16)
//        -> squash -> priors -> dynamic routing(3) -> fc1(relu) -> fc2
// B=2048. conv2 + fc1 via bf16 MFMA (16x16x32); rest fp32 vector.
// h is stored bf16-only ([B][3616], zero-padded) - feeds both pcaps and fc1.
// conv2 B-matrix: pre-converted to bf16 [tap][oc64][ic32] in global (k_w2conv),
// loaded straight to registers (no LDS staging, no barriers in tap loop).
// ---------------------------------------------------------------------------

#define BATCH 2048

typedef __attribute__((ext_vector_type(8))) short short8;
typedef __attribute__((ext_vector_type(4))) float floatx4;
typedef unsigned short u16;
typedef unsigned int   u32;

__device__ inline float wave_sum(float v) {
#pragma unroll
    for (int off = 32; off >= 1; off >>= 1) v += __shfl_xor(v, off);
    return v;
}
__device__ inline float wave_max(float v) {
#pragma unroll
    for (int off = 32; off >= 1; off >>= 1) v = fmaxf(v, __shfl_xor(v, off));
    return v;
}
__device__ inline u16 f2bf(float f) {  // RNE fp32->bf16 (finite)
    u32 u = __float_as_uint(f);
    u32 r = (u + 0x7FFFu + ((u >> 16) & 1u)) >> 16;
    return (u16)r;
}

// ---------- Kernel 0a: fc1 weights -> bf16 [512][3616] ---------------------
__global__ __launch_bounds__(256) void k_wconv(const float* __restrict__ fw,
                                               u16* __restrict__ w_bf) {
    int g  = blockIdx.x * 256 + threadIdx.x;  // one 8-short group (3616%8==0)
    int n  = (g * 8) / 3616;
    int k0 = (g * 8) % 3616;
    u16 v[8];
#pragma unroll
    for (int j = 0; j < 8; ++j) {
        int k = k0 + j;
        float f = (n < 500 && k < 3600) ? fw[(size_t)n * 3602 + k] : 0.f;
        v[j] = f2bf(f);
    }
    *(short8*)&w_bf[(size_t)g * 8] = *(short8*)v;
}

// ---------- Kernel 0b: conv2 weights -> bf16 [25][64][32] ------------------
__global__ __launch_bounds__(256) void k_w2conv(const float* __restrict__ w2,
                                                u16* __restrict__ w2t) {
    int g = blockIdx.x * 256 + threadIdx.x;   // 6400 groups of 8 = 51200
    if (g >= 6400) return;
    int idx = g * 8;
    int tap = idx >> 11;           // /2048
    int oc  = (idx >> 5) & 63;
    int ic0 = idx & 31;
    u16 v[8];
#pragma unroll
    for (int j = 0; j < 8; ++j) {
        int ic = ic0 + j;
        float f = (ic < 20 && oc < 50) ? w2[oc * 500 + ic * 25 + tap] : 0.f;
        v[j] = f2bf(f);
    }
    *(short8*)&w2t[idx] = *(short8*)v;
}

// ---------- Kernel 1: conv1+pool2 (fp32) + conv2+pool2 (bf16 MFMA) ---------
// x:[B,1,36,60] w1:[20,1,5,5] b1:[20] w2t:[25][64][32] bf16 b2:[50]
// h_bf:[B][3616] bf16 (oc*72 + ph*12 + pw; 3600..3615 zero)
__global__ __launch_bounds__(256, 3) void k_convs(
    const float* __restrict__ x, const float* __restrict__ w1,
    const float* __restrict__ b1, const u16* __restrict__ w2t,
    const float* __restrict__ b2, u32* __restrict__ h_bf)
{
    __shared__ __align__(16) u16 h1t[17920];   // 16*28*40 bf16, 35840 B
    __shared__ __align__(16) float sbuf[2732]; // xs[36*62] + w1s[500], 10928 B
    float* xs  = sbuf;
    float* w1s = sbuf + 2232;

    const int t = threadIdx.x;
    const int b = blockIdx.x;

    // zero only the ic pad [20,32) of each row (shorts 32..39 are never read)
    for (int i = t; i < 2688; i += 256) {
        int pos = i / 6, c = i - 6 * pos;
        ((u32*)h1t)[pos * 20 + 10 + c] = 0u;
    }
    const float* xb = x + b * 2160;
    for (int i = t; i < 2160; i += 256) {
        int r = i / 60, c = i - 60 * r;
        xs[r * 62 + c] = xb[i];
    }
    for (int i = t; i < 500; i += 256) w1s[i] = w1[i];
    __syncthreads();

    // conv1 + pool -> h1t[y][x][oc] bf16
#pragma unroll 1
    for (int u = t; u < 1280; u += 256) {
        int oc = u % 20;
        int g  = u / 20;
        int xg = g & 3;
        int y  = g >> 2;
        float wv[25];
#pragma unroll
        for (int j = 0; j < 25; ++j) wv[j] = w1s[oc * 25 + j];
        float acc[7][4];
#pragma unroll
        for (int p = 0; p < 7; ++p)
#pragma unroll
            for (int qq = 0; qq < 4; ++qq) acc[p][qq] = 0.f;
#pragma unroll
        for (int r = 0; r < 6; ++r) {
            float row[18];
            const float* src = &xs[(2 * y + r) * 62 + 14 * xg];
#pragma unroll
            for (int k = 0; k < 9; ++k) {
                float2 v = *(const float2*)&src[2 * k];
                row[2 * k] = v.x; row[2 * k + 1] = v.y;
            }
#pragma unroll
            for (int p = 0; p < 7; ++p)
#pragma unroll
                for (int s = 0; s < 5; ++s) {
                    float x0 = row[2 * p + s], x1 = row[2 * p + 1 + s];
                    if (r < 5) {
                        float w = wv[r * 5 + s];
                        acc[p][0] += x0 * w; acc[p][1] += x1 * w;
                    }
                    if (r >= 1) {
                        float w = wv[(r - 1) * 5 + s];
                        acc[p][2] += x0 * w; acc[p][3] += x1 * w;
                    }
                }
        }
        float bias = b1[oc];
#pragma unroll
        for (int p = 0; p < 7; ++p) {
            float v = bias + fmaxf(fmaxf(acc[p][0], acc[p][1]),
                                   fmaxf(acc[p][2], acc[p][3]));
            h1t[(y * 28 + 7 * xg + p) * 40 + oc] = f2bf(v);
        }
    }
    __syncthreads();  // h1t complete; conv2 reads it (no writes until pool stage)

    // conv2 via MFMA: M=288 Z-ordered pre-pool positions, N=64, K=32, 25 taps
    const int lane = t & 63, w = t >> 6;
    const int r16  = lane & 15;
    const int q    = lane >> 4;
    int abase[5];
#pragma unroll
    for (int i = 0; i < 5; ++i) {
        int mt = w + 4 * i;
        if (mt < 18) {
            int m  = mt * 16 + r16;
            int pq = m >> 2, sub = m & 3;
            int py = pq / 12, px = pq - py * 12;
            int yy = py * 2 + (sub >> 1);
            int xx = px * 2 + (sub & 1);
            abase[i] = (yy * 28 + xx) * 40 + q * 8;
        } else abase[i] = 0;
    }
    floatx4 acc2[5][4] = {};
    const u16* wtb = w2t + r16 * 32 + q * 8;  // + tap*2048 + nt*512

    short8 bf[4];
#pragma unroll
    for (int nt = 0; nt < 4; ++nt)
        bf[nt] = *(const short8*)&wtb[nt * 512];

#pragma unroll 1
    for (int tap = 0; tap < 25; ++tap) {
        short8 bfn[4];
        if (tap < 24) {
#pragma unroll
            for (int nt = 0; nt < 4; ++nt)
                bfn[nt] = *(const short8*)&wtb[(tap + 1) * 2048 + nt * 512];
        }
        int r = tap / 5, s = tap - 5 * r;
        int aoff = r * 1120 + s * 40;
#pragma unroll
        for (int i = 0; i < 5; ++i) {
            int mt = w + 4 * i;
            if (mt < 18) {
                short8 af = *(const short8*)&h1t[abase[i] + aoff];
#pragma unroll
                for (int nt = 0; nt < 4; ++nt)
                    acc2[i][nt] = __builtin_amdgcn_mfma_f32_16x16x32_bf16(
                        af, bf[nt], acc2[i][nt], 0, 0, 0);
            }
        }
#pragma unroll
        for (int nt = 0; nt < 4; ++nt) bf[nt] = bfn[nt];
    }
    __syncthreads();  // all A-reads of h1t done; reuse h1t as f32 out-stage

    // pool (lane-local quad: Z-order) -> f32 stage in LDS
    float* hs2 = (float*)h1t;  // 3600 f32
#pragma unroll
    for (int i = 0; i < 5; ++i) {
        int mt = w + 4 * i;
        if (mt < 18) {
            int pq = mt * 4 + q;
#pragma unroll
            for (int nt = 0; nt < 4; ++nt) {
                int oc = nt * 16 + r16;
                if (oc < 50) {
                    floatx4 a = acc2[i][nt];
                    float v = fmaxf(fmaxf(a[0], a[1]), fmaxf(a[2], a[3])) + b2[oc];
                    hs2[oc * 72 + pq] = v;
                }
            }
        }
    }
    __syncthreads();
    // pack to bf16 (zero tail 3600..3615)
    u32* ho = h_bf + (size_t)b * 1808;
    for (int i = t; i < 1808; i += 256) {
        int i2 = 2 * i;
        u32 lo = (i2 < 3600) ? f2bf(hs2[i2]) : 0u;
        u32 hi = (i2 + 1 < 3600) ? f2bf(hs2[i2 + 1]) : 0u;
        ho[i] = lo | (hi << 16);
    }
}

// ---------- Kernel 2: pcaps conv(pad2) + squash + priors -------------------
__global__ __launch_bounds__(256, 2) void k_pcaps(
    const u32* __restrict__ h_bf, const float* __restrict__ pcw,
    const float* __restrict__ pcb, const float* __restrict__ rw,
    float* __restrict__ priors)
{
    __shared__ __align__(16) float hs[3616];
    __shared__ __align__(16) float psum[5 * 1152];
    const int t = threadIdx.x;
    const int b = blockIdx.x;
    {
        const u32* hb = h_bf + (size_t)b * 1808;
        for (int i = t; i < 1808; i += 256) {
            u32 u = hb[i];
            hs[2 * i]     = __uint_as_float(u << 16);
            hs[2 * i + 1] = __uint_as_float(u & 0xFFFF0000u);
        }
    }
    __syncthreads();

    if (t < 240) {
        const int icq = t / 48;
        const int r48 = t % 48;
        const int ocg = r48 / 6;
        const int y   = r48 % 6;
        const int oc0 = 2 * ocg, oc1 = 2 * ocg + 1;
        float a0[12], a1[12];
#pragma unroll
        for (int xx = 0; xx < 12; ++xx) { a0[xx] = 0.f; a1[xx] = 0.f; }
#pragma unroll 1
        for (int ii = 0; ii < 10; ++ii) {
            int ic = icq * 10 + ii;
            float wv0[25], wv1[25];
            const float* p0 = pcw + (oc0 * 50 + ic) * 25;
            const float* p1 = pcw + (oc1 * 50 + ic) * 25;
#pragma unroll
            for (int j = 0; j < 25; ++j) { wv0[j] = p0[j]; wv1[j] = p1[j]; }
#pragma unroll
            for (int r = 0; r < 5; ++r) {
                int ry = y + r - 2;
                if ((unsigned)ry < 6u) {
                    const float* rowp = &hs[ic * 72 + ry * 12];
                    float row[12];
#pragma unroll
                    for (int k = 0; k < 3; ++k) {
                        float4 v = *(const float4*)&rowp[4 * k];
                        row[4 * k] = v.x; row[4 * k + 1] = v.y;
                        row[4 * k + 2] = v.z; row[4 * k + 3] = v.w;
                    }
#pragma unroll
                    for (int xx = 0; xx < 12; ++xx)
#pragma unroll
                        for (int s = 0; s < 5; ++s) {
                            int xi = xx + s - 2;
                            if (xi >= 0 && xi < 12) {
                                float xv = row[xi];
                                a0[xx] += xv * wv0[r * 5 + s];
                                a1[xx] += xv * wv1[r * 5 + s];
                            }
                        }
                }
            }
        }
        float* q0 = &psum[(icq * 16 + oc0) * 72 + y * 12];
        float* q1 = &psum[(icq * 16 + oc1) * 72 + y * 12];
#pragma unroll
        for (int k = 0; k < 3; ++k) {
            *(float4*)&q0[4 * k] = make_float4(a0[4*k], a0[4*k+1], a0[4*k+2], a0[4*k+3]);
            *(float4*)&q1[4 * k] = make_float4(a1[4*k], a1[4*k+1], a1[4*k+2], a1[4*k+3]);
        }
    }
    __syncthreads();

    for (int i = t; i < 1152; i += 256) {
        float s = psum[i] + psum[1152 + i] + psum[2 * 1152 + i]
                + psum[3 * 1152 + i] + psum[4 * 1152 + i] + pcb[i / 72];
        psum[i] = s;
    }
    __syncthreads();

    for (int r = t; r < 288; r += 256) {
        int sub = r / 72;
        int pos = r - sub * 72;
        float u0 = psum[(0 * 4 + sub) * 72 + pos];
        float u1 = psum[(1 * 4 + sub) * 72 + pos];
        float u2 = psum[(2 * 4 + sub) * 72 + pos];
        float u3 = psum[(3 * 4 + sub) * 72 + pos];
        float n2 = u0 * u0 + u1 * u1 + u2 * u2 + u3 * u3;
        float scale = (n2 / (1.0f + n2)) * rsqrtf(n2);
        u0 *= scale; u1 *= scale; u2 *= scale; u3 *= scale;
#pragma unroll
        for (int k = 0; k < 2; ++k) {
            const float* w = &rw[(k * 288 + r) * 4];
            priors[(k * BATCH + b) * 288 + r] =
                u0 * w[0] + u1 * w[1] + u2 * w[2] + u3 * w[3];
        }
    }
}

// ---------- Kernel 3: dynamic routing (3 iters), one wave per (k,b) --------
__global__ __launch_bounds__(256) void k_route(
    const float* __restrict__ priors, float* __restrict__ c)
{
    int wg   = blockIdx.x * 4 + (threadIdx.x >> 6);
    int lane = threadIdx.x & 63;
    int b = wg >> 1, k = wg & 1;
    const float* pr = priors + (k * BATCH + b) * 288;
    float p[5];
    bool  val[5];
#pragma unroll
    for (int j = 0; j < 5; ++j) {
        int r  = j * 64 + lane;
        val[j] = r < 288;
        p[j]   = val[j] ? pr[r] : 0.0f;
    }
    float tot = wave_sum(p[0] + p[1] + p[2] + p[3] + p[4]);
    float s = tot * (1.0f / 288.0f);
    float a = s * fabsf(s) / (1.0f + s * s);
#pragma unroll
    for (int it = 0; it < 2; ++it) {
        float l[5];
        float lm = -INFINITY;
#pragma unroll
        for (int j = 0; j < 5; ++j) {
            l[j] = val[j] ? p[j] * a : -INFINITY;
            lm   = fmaxf(lm, l[j]);
        }
        lm = wave_max(lm);
        float se = 0.f, sp = 0.f;
#pragma unroll
        for (int j = 0; j < 5; ++j) {
            float e = val[j] ? expf(l[j] - lm) : 0.f;
            se += e;
            sp += e * p[j];
        }
        se = wave_sum(se);
        sp = wave_sum(sp);
        float sv = sp / se;
        float v  = sv * fabsf(sv) / (1.0f + sv * sv);
        if (it == 0) a += v;
        else if (lane == 0) c[b * 2 + k] = v;
    }
}

// ---------- Kernel 4: fc1 bf16 MFMA GEMM [2048,3616]x[512,3616]^T ----------
__global__ __launch_bounds__(256) void k_fc1(
    const u16* __restrict__ h_bf, const u16* __restrict__ w_bf,
    const float* __restrict__ cc, const float* __restrict__ w,
    const float* __restrict__ bias, float* __restrict__ f1)
{
    __shared__ __align__(16) u16 As[64 * 40];  // pitch 40 shorts (80B)
    __shared__ __align__(16) u16 Bs[64 * 40];
    const int t  = threadIdx.x;
    const int m0 = blockIdx.x * 64;
    const int n0 = blockIdx.y * 64;
    const int row = t >> 2, c8 = (t & 3) * 8;
    const u16* ha = &h_bf[(size_t)(m0 + row) * 3616 + c8];
    const u16* wa = &w_bf[(size_t)(n0 + row) * 3616 + c8];
    short8 areg = *(const short8*)ha;
    short8 breg = *(const short8*)wa;
    const int lane = t & 63, wv = t >> 6;
    const int r16 = lane & 15, q = lane >> 4;
    const int wr = row * 40 + (t & 3) * 8;
    const int ar = (wv * 16 + r16) * 40 + q * 8;
    const int br = r16 * 40 + q * 8;
    floatx4 acc[4] = {};
#pragma unroll 1
    for (int it = 0; it < 113; ++it) {
        __syncthreads();
        *(short8*)&As[wr] = areg;
        *(short8*)&Bs[wr] = breg;
        __syncthreads();
        if (it < 112) {
            areg = *(const short8*)(ha + (it + 1) * 32);
            breg = *(const short8*)(wa + (it + 1) * 32);
        }
        short8 af = *(const short8*)&As[ar];
#pragma unroll
        for (int nt = 0; nt < 4; ++nt) {
            short8 bf = *(const short8*)&Bs[nt * 640 + br];
            acc[nt] = __builtin_amdgcn_mfma_f32_16x16x32_bf16(af, bf, acc[nt], 0, 0, 0);
        }
    }
    const int mbase = m0 + wv * 16 + q * 4;
#pragma unroll
    for (int nt = 0; nt < 4; ++nt) {
        int n = n0 + nt * 16 + r16;
        if (n < 500) {
            float bn  = bias[n];
            float wc0 = w[(size_t)n * 3602 + 3600];
            float wc1 = w[(size_t)n * 3602 + 3601];
#pragma unroll
            for (int i = 0; i < 4; ++i) {
                int m = mbase + i;
                float v = acc[nt][i] + bn + cc[m * 2] * wc0 + cc[m * 2 + 1] * wc1;
                f1[(size_t)m * 500 + n] = fmaxf(v, 0.f);
            }
        }
    }
}

// ---------- Kernel 5: fc2, one wave per (b,j) ------------------------------
__global__ __launch_bounds__(256) void k_fc2(
    const float* __restrict__ f1, const float* __restrict__ y,
    const float* __restrict__ w, const float* __restrict__ bias,
    float* __restrict__ out)
{
    int wg   = blockIdx.x * 4 + (threadIdx.x >> 6);
    int lane = threadIdx.x & 63;
    int b = wg >> 1, j = wg & 1;
    const float* wj = w + j * 502;
    float acc = 0.f;
    for (int k = lane; k < 500; k += 64) acc += f1[(size_t)b * 500 + k] * wj[k];
    if (lane < 2) acc += y[b * 2 + lane] * wj[500 + lane];
    acc = wave_sum(acc);
    if (lane == 0) out[b * 2 + j] = acc + bias[j];
}

// ---------------------------------------------------------------------------
extern "C" void kernel_launch(void* const* d_in, const int* in_sizes, int n_in,
                              void* d_out, int out_size, void* d_ws, size_t ws_size,
                              hipStream_t stream) {
    const float* x    = (const float*)d_in[0];
    const float* y    = (const float*)d_in[1];
    const float* c1w  = (const float*)d_in[2];
    const float* c1b  = (const float*)d_in[3];
    const float* c2w  = (const float*)d_in[4];
    const float* c2b  = (const float*)d_in[5];
    const float* pcw  = (const float*)d_in[6];
    const float* pcb  = (const float*)d_in[7];
    const float* rw   = (const float*)d_in[8];
    const float* f1w  = (const float*)d_in[9];
    const float* f1b  = (const float*)d_in[10];
    const float* f2w  = (const float*)d_in[11];
    const float* f2b  = (const float*)d_in[12];
    float* out = (float*)d_out;

    // workspace layout
    u32*   h_bf   = (u32*)d_ws;                           // 2048*1808 u32
    u16*   w_bf   = (u16*)(h_bf + (size_t)BATCH * 1808);  // 512*3616 u16
    u16*   w2t    = w_bf + (size_t)512 * 3616;            // 25*64*32 u16
    float* priors = (float*)(w2t + 51200);                // 2*2048*288
    float* cbuf   = priors + 2 * BATCH * 288;             // 4096
    float* f1     = cbuf + BATCH * 2;                     // 2048*500

    k_wconv<<<904, 256, 0, stream>>>(f1w, w_bf);
    k_w2conv<<<25, 256, 0, stream>>>(c2w, w2t);
    k_convs<<<BATCH, 256, 0, stream>>>(x, c1w, c1b, w2t, c2b, h_bf);
    k_pcaps<<<BATCH, 256, 0, stream>>>(h_bf, pcw, pcb, rw, priors);
    k_route<<<BATCH * 2 / 4, 256, 0, stream>>>(priors, cbuf);
    dim3 g4(32, 8);
    k_fc1<<<g4, 256, 0, stream>>>((const u16*)h_bf, w_bf, cbuf, f1w, f1b, f1);
    k_fc2<<<BATCH * 2 / 4, 256, 0, stream>>>(f1, y, f2w, f2b, out);
}

// Round 6
// 279.584 us; speedup vs baseline: 6.0891x; 1.1850x over previous
//
#include <hip/hip_runtime.h>
#include <math.h>

// ---------------------------------------------------------------------------
// Model: conv1(5x5,20)+pool2 -> conv2(5x5,50)+pool2 -> pcaps(5x5 pad2,16)
//        -> squash -> priors -> dynamic routing(3) -> fc1(relu) -> fc2
// B=2048. conv2 + pcaps + fc1 via bf16 MFMA (16x16x32); rest fp32 vector.
// h_bf global layout is POSITION-MAJOR: k' = pos*50 + oc (pos = ph*12+pw),
// padded to 3616. fc1 weights are permuted to match in k_wconv.
// pcaps is a per-tap MFMA GEMM (M=72 pos, N=16 oc, K=50 ic) with routing
// fused into the same block (priors never touch global memory).
// ---------------------------------------------------------------------------

#define BATCH 2048

typedef __attribute__((ext_vector_type(8))) short short8;
typedef __attribute__((ext_vector_type(4))) float floatx4;
typedef unsigned short u16;
typedef unsigned int   u32;

__device__ inline float wave_sum(float v) {
#pragma unroll
    for (int off = 32; off >= 1; off >>= 1) v += __shfl_xor(v, off);
    return v;
}
__device__ inline float wave_max(float v) {
#pragma unroll
    for (int off = 32; off >= 1; off >>= 1) v = fmaxf(v, __shfl_xor(v, off));
    return v;
}
__device__ inline u16 f2bf(float f) {  // RNE fp32->bf16 (finite)
    u32 u = __float_as_uint(f);
    u32 r = (u + 0x7FFFu + ((u >> 16) & 1u)) >> 16;
    return (u16)r;
}

// ---------- Kernel 0a: fc1 weights -> bf16 [512][3616], K permuted ---------
// w_bf[n][k'] with k' = pos*50 + oc  <->  reference k = oc*72 + pos
__global__ __launch_bounds__(256) void k_wconv(const float* __restrict__ fw,
                                               u16* __restrict__ w_bf) {
    int g  = blockIdx.x * 256 + threadIdx.x;
    int n  = (g * 8) / 3616;
    int k0 = (g * 8) % 3616;
    u16 v[8];
#pragma unroll
    for (int j = 0; j < 8; ++j) {
        int kk = k0 + j;
        float f = 0.f;
        if (n < 500 && kk < 3600) {
            int pos = kk / 50;
            int oc  = kk - 50 * pos;
            f = fw[(size_t)n * 3602 + oc * 72 + pos];
        }
        v[j] = f2bf(f);
    }
    *(short8*)&w_bf[(size_t)g * 8] = *(short8*)v;
}

// ---------- Kernel 0b: conv2 weights -> bf16 [25][64][32] ------------------
__global__ __launch_bounds__(256) void k_w2conv(const float* __restrict__ w2,
                                                u16* __restrict__ w2t) {
    int g = blockIdx.x * 256 + threadIdx.x;   // 6400 groups of 8
    if (g >= 6400) return;
    int idx = g * 8;
    int tap = idx >> 11;
    int oc  = (idx >> 5) & 63;
    int ic0 = idx & 31;
    u16 v[8];
#pragma unroll
    for (int j = 0; j < 8; ++j) {
        int ic = ic0 + j;
        float f = (ic < 20 && oc < 50) ? w2[oc * 500 + ic * 25 + tap] : 0.f;
        v[j] = f2bf(f);
    }
    *(short8*)&w2t[idx] = *(short8*)v;
}

// ---------- Kernel 0c: pcaps weights -> bf16 [25][16][64] ------------------
__global__ __launch_bounds__(256) void k_pwconv(const float* __restrict__ pcw,
                                                u16* __restrict__ w_pc) {
    int g = blockIdx.x * 256 + threadIdx.x;   // 3200 groups of 8
    if (g >= 3200) return;
    int idx = g * 8;
    int tap = idx >> 10;
    int rem = idx & 1023;
    int oc  = rem >> 6;
    int ic0 = rem & 63;
    u16 v[8];
#pragma unroll
    for (int j = 0; j < 8; ++j) {
        int ic = ic0 + j;
        float f = (ic < 50) ? pcw[(oc * 50 + ic) * 25 + tap] : 0.f;
        v[j] = f2bf(f);
    }
    *(short8*)&w_pc[idx] = *(short8*)v;
}

// ---------- Kernel 1: conv1+pool2 (fp32) + conv2+pool2 (bf16 MFMA) ---------
// h_bf:[B][3616] bf16, k' = pos*50 + oc (3600..3615 zero)
__global__ __launch_bounds__(256, 3) void k_convs(
    const float* __restrict__ x, const float* __restrict__ w1,
    const float* __restrict__ b1, const u16* __restrict__ w2t,
    const float* __restrict__ b2, u32* __restrict__ h_bf)
{
    __shared__ __align__(16) u16 h1t[17920];   // 16*28*40 bf16, 35840 B
    __shared__ __align__(16) float sbuf[2732]; // xs[36*62] + w1s[500]
    float* xs  = sbuf;
    float* w1s = sbuf + 2232;

    const int t = threadIdx.x;
    const int b = blockIdx.x;

    // zero only the ic pad [20,32) of each row
    for (int i = t; i < 2688; i += 256) {
        int pos = i / 6, c = i - 6 * pos;
        ((u32*)h1t)[pos * 20 + 10 + c] = 0u;
    }
    const float* xb = x + b * 2160;
    for (int i = t; i < 2160; i += 256) {
        int r = i / 60, c = i - 60 * r;
        xs[r * 62 + c] = xb[i];
    }
    for (int i = t; i < 500; i += 256) w1s[i] = w1[i];
    __syncthreads();

    // conv1 + pool -> h1t[y][x][oc] bf16
#pragma unroll 1
    for (int u = t; u < 1280; u += 256) {
        int oc = u % 20;
        int g  = u / 20;
        int xg = g & 3;
        int y  = g >> 2;
        float wv[25];
#pragma unroll
        for (int j = 0; j < 25; ++j) wv[j] = w1s[oc * 25 + j];
        float acc[7][4];
#pragma unroll
        for (int p = 0; p < 7; ++p)
#pragma unroll
            for (int qq = 0; qq < 4; ++qq) acc[p][qq] = 0.f;
#pragma unroll
        for (int r = 0; r < 6; ++r) {
            float row[18];
            const float* src = &xs[(2 * y + r) * 62 + 14 * xg];
#pragma unroll
            for (int k = 0; k < 9; ++k) {
                float2 v = *(const float2*)&src[2 * k];
                row[2 * k] = v.x; row[2 * k + 1] = v.y;
            }
#pragma unroll
            for (int p = 0; p < 7; ++p)
#pragma unroll
                for (int s = 0; s < 5; ++s) {
                    float x0 = row[2 * p + s], x1 = row[2 * p + 1 + s];
                    if (r < 5) {
                        float w = wv[r * 5 + s];
                        acc[p][0] += x0 * w; acc[p][1] += x1 * w;
                    }
                    if (r >= 1) {
                        float w = wv[(r - 1) * 5 + s];
                        acc[p][2] += x0 * w; acc[p][3] += x1 * w;
                    }
                }
        }
        float bias = b1[oc];
#pragma unroll
        for (int p = 0; p < 7; ++p) {
            float v = bias + fmaxf(fmaxf(acc[p][0], acc[p][1]),
                                   fmaxf(acc[p][2], acc[p][3]));
            h1t[(y * 28 + 7 * xg + p) * 40 + oc] = f2bf(v);
        }
    }
    __syncthreads();

    // conv2 via MFMA: M=288 Z-ordered pre-pool positions, N=64, K=32, 25 taps
    const int lane = t & 63, w = t >> 6;
    const int r16  = lane & 15;
    const int q    = lane >> 4;
    int abase[5];
#pragma unroll
    for (int i = 0; i < 5; ++i) {
        int mt = w + 4 * i;
        if (mt < 18) {
            int m  = mt * 16 + r16;
            int pq = m >> 2, sub = m & 3;
            int py = pq / 12, px = pq - py * 12;
            int yy = py * 2 + (sub >> 1);
            int xx = px * 2 + (sub & 1);
            abase[i] = (yy * 28 + xx) * 40 + q * 8;
        } else abase[i] = 0;
    }
    floatx4 acc2[5][4] = {};
    const u16* wtb = w2t + r16 * 32 + q * 8;

    short8 bf[4];
#pragma unroll
    for (int nt = 0; nt < 4; ++nt)
        bf[nt] = *(const short8*)&wtb[nt * 512];

#pragma unroll 1
    for (int tap = 0; tap < 25; ++tap) {
        short8 bfn[4];
        if (tap < 24) {
#pragma unroll
            for (int nt = 0; nt < 4; ++nt)
                bfn[nt] = *(const short8*)&wtb[(tap + 1) * 2048 + nt * 512];
        }
        int r = tap / 5, s = tap - 5 * r;
        int aoff = r * 1120 + s * 40;
#pragma unroll
        for (int i = 0; i < 5; ++i) {
            int mt = w + 4 * i;
            if (mt < 18) {
                short8 af = *(const short8*)&h1t[abase[i] + aoff];
#pragma unroll
                for (int nt = 0; nt < 4; ++nt)
                    acc2[i][nt] = __builtin_amdgcn_mfma_f32_16x16x32_bf16(
                        af, bf[nt], acc2[i][nt], 0, 0, 0);
            }
        }
#pragma unroll
        for (int nt = 0; nt < 4; ++nt) bf[nt] = bfn[nt];
    }
    __syncthreads();  // all A-reads of h1t done; reuse as f32 out-stage

    // pool -> hs2[pos*50 + oc] (position-major)
    float* hs2 = (float*)h1t;  // 3600 f32
#pragma unroll
    for (int i = 0; i < 5; ++i) {
        int mt = w + 4 * i;
        if (mt < 18) {
            int pq = mt * 4 + q;   // = pos
#pragma unroll
            for (int nt = 0; nt < 4; ++nt) {
                int oc = nt * 16 + r16;
                if (oc < 50) {
                    floatx4 a = acc2[i][nt];
                    float v = fmaxf(fmaxf(a[0], a[1]), fmaxf(a[2], a[3])) + b2[oc];
                    hs2[pq * 50 + oc] = v;
                }
            }
        }
    }
    __syncthreads();
    // pack to bf16 (zero tail 3600..3615)
    u32* ho = h_bf + (size_t)b * 1808;
    for (int i = t; i < 1808; i += 256) {
        int i2 = 2 * i;
        u32 lo = (i2 < 3600) ? f2bf(hs2[i2]) : 0u;
        u32 hi = (i2 + 1 < 3600) ? f2bf(hs2[i2 + 1]) : 0u;
        ho[i] = lo | (hi << 16);
    }
}

// ---------- Kernel 2: pcaps (bf16 MFMA) + squash + priors + routing --------
// h_bf:[B][3616] bf16 pos-major; w_pc:[25][16][64] bf16; rw:[2,288,4]
// out: cbuf[B][2]
// GEMM per tap: M=72 pos (5 m-tiles, last masked), N=16 oc, K=64 (50 ic).
// hs[y0..9+ovf][x0..15][ic pitch 72] bf16 zero-padded spatially.
__global__ __launch_bounds__(256) void k_pcaps(
    const u32* __restrict__ h_bf, const u16* __restrict__ w_pc,
    const float* __restrict__ pcb, const float* __restrict__ rw,
    float* __restrict__ cbuf)
{
    __shared__ __align__(16) u16 hsbuf[12672];  // 176 rows x 72 shorts, 25344 B
    __shared__ __align__(16) float pri[576];
    const int t = threadIdx.x;
    const int b = blockIdx.x;

    // zero (borders + overflow rows + ic pad)
    for (int i = t; i < 6336; i += 256) ((u32*)hsbuf)[i] = 0u;
    __syncthreads();
    // stage h: k' = pos*50 + oc -> hs[(ph+2)*16 + pw+2][oc]
    {
        const u32* hb = h_bf + (size_t)b * 1808;
        for (int i = t; i < 1800; i += 256) {
            u32 v   = hb[i];
            int k2  = 2 * i;
            int pos = k2 / 50;
            int oc  = k2 - 50 * pos;   // even
            int ph  = pos / 12, pw = pos - 12 * ph;
            ((u32*)hsbuf)[((((ph + 2) * 16) + pw + 2) * 72 + oc) >> 1] = v;
        }
    }
    __syncthreads();

    const int lane = t & 63, w = t >> 6;
    const int r16  = lane & 15;
    const int q    = lane >> 4;
    int abase[5];
#pragma unroll
    for (int mt = 0; mt < 5; ++mt) {
        int m  = mt * 16 + r16;       // pos (72..79 read zero rows)
        int ph = m / 12, pw = m - 12 * ph;
        abase[mt] = (ph * 16 + pw) * 72 + q * 8;
    }
    floatx4 acc[5] = {};
    const u16* wp = w_pc + r16 * 64 + q * 8;
    const int ntap = (28 - w) >> 2;   // 7,6,6,6
#pragma unroll 1
    for (int tt = 0; tt < ntap; ++tt) {
        int tap = w + 4 * tt;
        short8 b0 = *(const short8*)&wp[tap * 1024];
        short8 b1 = *(const short8*)&wp[tap * 1024 + 32];
        int r = tap / 5, s = tap - 5 * r;
        int aoff = (r * 16 + s) * 72;
#pragma unroll
        for (int mt = 0; mt < 5; ++mt) {
            short8 a0 = *(const short8*)&hsbuf[abase[mt] + aoff];
            short8 a1 = *(const short8*)&hsbuf[abase[mt] + aoff + 32];
            acc[mt] = __builtin_amdgcn_mfma_f32_16x16x32_bf16(a0, b0, acc[mt], 0, 0, 0);
            acc[mt] = __builtin_amdgcn_mfma_f32_16x16x32_bf16(a1, b1, acc[mt], 0, 0, 0);
        }
    }
    __syncthreads();  // hs reads done -> overlay psum

    // psum[w][m80][oc16] f32 (20480 B, overlays hsbuf)
    float* psum = (float*)hsbuf;
#pragma unroll
    for (int mt = 0; mt < 5; ++mt)
#pragma unroll
        for (int i = 0; i < 4; ++i) {
            int m = mt * 16 + q * 4 + i;
            psum[w * 1280 + m * 16 + r16] = acc[mt][i];
        }
    __syncthreads();

    // reduce 4 partials + bias (m<72 only); each thread reads/writes own i
    for (int i = t; i < 1152; i += 256) {
        float s = psum[i] + psum[1280 + i] + psum[2560 + i] + psum[3840 + i]
                + pcb[i & 15];
        psum[i] = s;
    }
    __syncthreads();

    // squash over capsule dim + priors -> pri[2][288]
    for (int r = t; r < 288; r += 256) {
        int sub = r / 72;
        int pos = r - sub * 72;
        float u0 = psum[pos * 16 + 0  + sub];
        float u1 = psum[pos * 16 + 4  + sub];
        float u2 = psum[pos * 16 + 8  + sub];
        float u3 = psum[pos * 16 + 12 + sub];
        float n2 = u0 * u0 + u1 * u1 + u2 * u2 + u3 * u3;
        float scale = (n2 / (1.0f + n2)) * rsqrtf(n2);
        u0 *= scale; u1 *= scale; u2 *= scale; u3 *= scale;
#pragma unroll
        for (int k = 0; k < 2; ++k) {
            const float4 wv = *(const float4*)&rw[(k * 288 + r) * 4];
            pri[k * 288 + r] = u0 * wv.x + u1 * wv.y + u2 * wv.z + u3 * wv.w;
        }
    }
    __syncthreads();

    // dynamic routing (3 iters): wave 0 -> k=0, wave 1 -> k=1
    if (w < 2) {
        const float* pr = &pri[w * 288];
        float p[5];
        bool  val[5];
#pragma unroll
        for (int j = 0; j < 5; ++j) {
            int r  = j * 64 + lane;
            val[j] = r < 288;
            p[j]   = val[j] ? pr[r] : 0.0f;
        }
        float tot = wave_sum(p[0] + p[1] + p[2] + p[3] + p[4]);
        float s = tot * (1.0f / 288.0f);
        float a = s * fabsf(s) / (1.0f + s * s);
#pragma unroll
        for (int it = 0; it < 2; ++it) {
            float l[5];
            float lm = -INFINITY;
#pragma unroll
            for (int j = 0; j < 5; ++j) {
                l[j] = val[j] ? p[j] * a : -INFINITY;
                lm   = fmaxf(lm, l[j]);
            }
            lm = wave_max(lm);
            float se = 0.f, sp = 0.f;
#pragma unroll
            for (int j = 0; j < 5; ++j) {
                float e = val[j] ? expf(l[j] - lm) : 0.f;
                se += e;
                sp += e * p[j];
            }
            se = wave_sum(se);
            sp = wave_sum(sp);
            float sv = sp / se;
            float v  = sv * fabsf(sv) / (1.0f + sv * sv);
            if (it == 0) a += v;
            else if (lane == 0) cbuf[b * 2 + w] = v;
        }
    }
}

// ---------- Kernel 4: fc1 bf16 MFMA GEMM [2048,3616]x[512,3616]^T ----------
__global__ __launch_bounds__(256) void k_fc1(
    const u16* __restrict__ h_bf, const u16* __restrict__ w_bf,
    const float* __restrict__ cc, const float* __restrict__ w,
    const float* __restrict__ bias, float* __restrict__ f1)
{
    __shared__ __align__(16) u16 As[64 * 40];  // pitch 40 shorts (80B)
    __shared__ __align__(16) u16 Bs[64 * 40];
    const int t  = threadIdx.x;
    const int m0 = blockIdx.x * 64;
    const int n0 = blockIdx.y * 64;
    const int row = t >> 2, c8 = (t & 3) * 8;
    const u16* ha = &h_bf[(size_t)(m0 + row) * 3616 + c8];
    const u16* wa = &w_bf[(size_t)(n0 + row) * 3616 + c8];
    short8 areg = *(const short8*)ha;
    short8 breg = *(const short8*)wa;
    const int lane = t & 63, wv = t >> 6;
    const int r16 = lane & 15, q = lane >> 4;
    const int wr = row * 40 + (t & 3) * 8;
    const int ar = (wv * 16 + r16) * 40 + q * 8;
    const int br = r16 * 40 + q * 8;
    floatx4 acc[4] = {};
#pragma unroll 1
    for (int it = 0; it < 113; ++it) {
        __syncthreads();
        *(short8*)&As[wr] = areg;
        *(short8*)&Bs[wr] = breg;
        __syncthreads();
        if (it < 112) {
            areg = *(const short8*)(ha + (it + 1) * 32);
            breg = *(const short8*)(wa + (it + 1) * 32);
        }
        short8 af = *(const short8*)&As[ar];
#pragma unroll
        for (int nt = 0; nt < 4; ++nt) {
            short8 bf = *(const short8*)&Bs[nt * 640 + br];
            acc[nt] = __builtin_amdgcn_mfma_f32_16x16x32_bf16(af, bf, acc[nt], 0, 0, 0);
        }
    }
    const int mbase = m0 + wv * 16 + q * 4;
#pragma unroll
    for (int nt = 0; nt < 4; ++nt) {
        int n = n0 + nt * 16 + r16;
        if (n < 500) {
            float bn  = bias[n];
            float wc0 = w[(size_t)n * 3602 + 3600];
            float wc1 = w[(size_t)n * 3602 + 3601];
#pragma unroll
            for (int i = 0; i < 4; ++i) {
                int m = mbase + i;
                float v = acc[nt][i] + bn + cc[m * 2] * wc0 + cc[m * 2 + 1] * wc1;
                f1[(size_t)m * 500 + n] = fmaxf(v, 0.f);
            }
        }
    }
}

// ---------- Kernel 5: fc2, one wave per (b,j) ------------------------------
__global__ __launch_bounds__(256) void k_fc2(
    const float* __restrict__ f1, const float* __restrict__ y,
    const float* __restrict__ w, const float* __restrict__ bias,
    float* __restrict__ out)
{
    int wg   = blockIdx.x * 4 + (threadIdx.x >> 6);
    int lane = threadIdx.x & 63;
    int b = wg >> 1, j = wg & 1;
    const float* wj = w + j * 502;
    float acc = 0.f;
    for (int k = lane; k < 500; k += 64) acc += f1[(size_t)b * 500 + k] * wj[k];
    if (lane < 2) acc += y[b * 2 + lane] * wj[500 + lane];
    acc = wave_sum(acc);
    if (lane == 0) out[b * 2 + j] = acc + bias[j];
}

// ---------------------------------------------------------------------------
extern "C" void kernel_launch(void* const* d_in, const int* in_sizes, int n_in,
                              void* d_out, int out_size, void* d_ws, size_t ws_size,
                              hipStream_t stream) {
    const float* x    = (const float*)d_in[0];
    const float* y    = (const float*)d_in[1];
    const float* c1w  = (const float*)d_in[2];
    const float* c1b  = (const float*)d_in[3];
    const float* c2w  = (const float*)d_in[4];
    const float* c2b  = (const float*)d_in[5];
    const float* pcw  = (const float*)d_in[6];
    const float* pcb  = (const float*)d_in[7];
    const float* rw   = (const float*)d_in[8];
    const float* f1w  = (const float*)d_in[9];
    const float* f1b  = (const float*)d_in[10];
    const float* f2w  = (const float*)d_in[11];
    const float* f2b  = (const float*)d_in[12];
    float* out = (float*)d_out;

    // workspace layout
    u32*   h_bf   = (u32*)d_ws;                           // 2048*1808 u32
    u16*   w_bf   = (u16*)(h_bf + (size_t)BATCH * 1808);  // 512*3616 u16
    u16*   w2t    = w_bf + (size_t)512 * 3616;            // 25*64*32 u16
    u16*   w_pc   = w2t + 51200;                          // 25*16*64 u16
    float* cbuf   = (float*)(w_pc + 25600);               // 4096 f32
    float* f1     = cbuf + BATCH * 2;                     // 2048*500 f32

    k_wconv<<<904, 256, 0, stream>>>(f1w, w_bf);
    k_w2conv<<<25, 256, 0, stream>>>(c2w, w2t);
    k_pwconv<<<13, 256, 0, stream>>>(pcw, w_pc);
    k_convs<<<BATCH, 256, 0, stream>>>(x, c1w, c1b, w2t, c2b, h_bf);
    k_pcaps<<<BATCH, 256, 0, stream>>>(h_bf, w_pc, pcb, rw, cbuf);
    dim3 g4(32, 8);
    k_fc1<<<g4, 256, 0, stream>>>((const u16*)h_bf, w_bf, cbuf, f1w, f1b, f1);
    k_fc2<<<BATCH * 2 / 4, 256, 0, stream>>>(f1, y, f2w, f2b, out);
}

// Round 7
// 271.065 us; speedup vs baseline: 6.2804x; 1.0314x over previous
//
#include <hip/hip_runtime.h>
#include <math.h>

// ---------------------------------------------------------------------------
// Model: conv1(5x5,20)+pool2 -> conv2(5x5,50)+pool2 -> pcaps(5x5 pad2,16)
//        -> squash -> priors -> dynamic routing(3) -> fc1(relu) -> fc2
// B=2048. conv1 + conv2 + pcaps + fc1 all via bf16 MFMA (16x16x32).
// h_bf global layout POSITION-MAJOR: k' = pos*50 + oc, padded to 3616.
// conv1: chunked in-LDS im2col GEMM (M=112/chunk, K=25->32 taps, N=20->32).
// ---------------------------------------------------------------------------

#define BATCH 2048

typedef __attribute__((ext_vector_type(8))) short short8;
typedef __attribute__((ext_vector_type(4))) float floatx4;
typedef unsigned short u16;
typedef unsigned int   u32;

__device__ inline float wave_sum(float v) {
#pragma unroll
    for (int off = 32; off >= 1; off >>= 1) v += __shfl_xor(v, off);
    return v;
}
__device__ inline float wave_max(float v) {
#pragma unroll
    for (int off = 32; off >= 1; off >>= 1) v = fmaxf(v, __shfl_xor(v, off));
    return v;
}
__device__ inline u16 f2bf(float f) {  // RNE fp32->bf16 (finite)
    u32 u = __float_as_uint(f);
    u32 r = (u + 0x7FFFu + ((u >> 16) & 1u)) >> 16;
    return (u16)r;
}

// ---------- Kernel 0: all weight conversions in one launch -----------------
// blk <  904 : fc1 weights -> w_bf[512][3616] bf16, K permuted (pos*50+oc)
// blk <  929 : conv2 weights -> w2t[25][64][32] bf16
// blk <  942 : pcaps weights -> w_pc[25][16][64] bf16
// blk == 942 : conv1 weights -> w1t[32][32] bf16 (B-layout [oc][tap])
__global__ __launch_bounds__(256) void k_prep(
    const float* __restrict__ fw,  u16* __restrict__ w_bf,
    const float* __restrict__ w2,  u16* __restrict__ w2t,
    const float* __restrict__ pcw, u16* __restrict__ w_pc,
    const float* __restrict__ w1,  u16* __restrict__ w1t)
{
    const int blk = blockIdx.x, t = threadIdx.x;
    if (blk < 904) {
        int g  = blk * 256 + t;
        int n  = (g * 8) / 3616;
        int k0 = (g * 8) % 3616;
        u16 v[8];
#pragma unroll
        for (int j = 0; j < 8; ++j) {
            int kk = k0 + j;
            float f = 0.f;
            if (n < 500 && kk < 3600) {
                int pos = kk / 50;
                int oc  = kk - 50 * pos;
                f = fw[(size_t)n * 3602 + oc * 72 + pos];
            }
            v[j] = f2bf(f);
        }
        *(short8*)&w_bf[(size_t)g * 8] = *(short8*)v;
    } else if (blk < 929) {
        int g   = (blk - 904) * 256 + t;
        int idx = g * 8;
        int tap = idx >> 11;
        int oc  = (idx >> 5) & 63;
        int ic0 = idx & 31;
        u16 v[8];
#pragma unroll
        for (int j = 0; j < 8; ++j) {
            int ic = ic0 + j;
            float f = (ic < 20 && oc < 50) ? w2[oc * 500 + ic * 25 + tap] : 0.f;
            v[j] = f2bf(f);
        }
        *(short8*)&w2t[idx] = *(short8*)v;
    } else if (blk < 942) {
        int g = (blk - 929) * 256 + t;
        if (g >= 3200) return;
        int idx = g * 8;
        int tap = idx >> 10;
        int rem = idx & 1023;
        int oc  = rem >> 6;
        int ic0 = rem & 63;
        u16 v[8];
#pragma unroll
        for (int j = 0; j < 8; ++j) {
            int ic = ic0 + j;
            float f = (ic < 50) ? pcw[(oc * 50 + ic) * 25 + tap] : 0.f;
            v[j] = f2bf(f);
        }
        *(short8*)&w_pc[idx] = *(short8*)v;
    } else {
        if (t < 128) {
            int n  = t >> 2;
            int k0 = (t & 3) * 8;
            u16 v[8];
#pragma unroll
            for (int j = 0; j < 8; ++j) {
                int k = k0 + j;
                float f = (n < 20 && k < 25) ? w1[n * 25 + k] : 0.f;
                v[j] = f2bf(f);
            }
            *(short8*)&w1t[t * 8] = *(short8*)v;
        }
    }
}

// ---------- Kernel 1: conv1 (bf16 MFMA im2col) + conv2 (bf16 MFMA) ---------
// x:[B,1,36,60]; w1t:[32][32] bf16; b1:[20]; w2t:[25][64][32] bf16; b2:[50]
// h_bf:[B][3616] bf16, k' = pos*50 + oc (3600..3615 zero)
__global__ __launch_bounds__(256, 3) void k_convs(
    const float* __restrict__ x, const u16* __restrict__ w1t,
    const float* __restrict__ b1, const u16* __restrict__ w2t,
    const float* __restrict__ b2, u32* __restrict__ h_bf)
{
    __shared__ __align__(16) u16 h1t[17920];  // [y16][x28][ic40] bf16, 35840 B
    __shared__ __align__(16) u16 xbf[2304];   // [36][64] bf16, 4608 B
    __shared__ __align__(16) u16 im2[4480];   // [112][40] bf16, 8960 B

    const int t = threadIdx.x;
    const int b = blockIdx.x;

    // zero the ic pad [20,32) of h1t rows; stage x as bf16
    for (int i = t; i < 2688; i += 256) {
        int pos = i / 6, c = i - 6 * pos;
        ((u32*)h1t)[pos * 20 + 10 + c] = 0u;
    }
    const float* xb = x + b * 2160;
    for (int i = t; i < 2160; i += 256) {
        int r = i / 60, c = i - 60 * r;
        xbf[r * 64 + c] = f2bf(xb[i]);
    }
    __syncthreads();

    const int lane = t & 63, w = t >> 6;
    const int r16  = lane & 15;
    const int q    = lane >> 4;

    // ---- conv1 via MFMA, 16 chunks of 2 pre-pool rows (112 positions) ----
    // Z-order: p = px*4 + dy*2 + dx  (px = pooled col, dy/dx in 2x2 quad)
    short8 w1f[2];
#pragma unroll
    for (int nt = 0; nt < 2; ++nt)
        w1f[nt] = *(const short8*)&w1t[(nt * 16 + r16) * 32 + q * 8];

    const int p_   = t;               // builder position (t<112)
    const int px_  = p_ >> 2;
    const int dy_  = (p_ & 3) >> 1, dx_ = p_ & 1;
    const int xc_  = 2 * px_ + dx_;   // 0..55
    const int j0_  = xc_ >> 1;
    const int par_ = xc_ & 1;

#pragma unroll 1
    for (int c = 0; c < 16; ++c) {
        if (t < 112) {
            u16 tap[25];
#pragma unroll
            for (int r = 0; r < 5; ++r) {
                const u32* U = (const u32*)&xbf[(2 * c + dy_ + r) * 64];
                u32 A0 = U[j0_], A1 = U[j0_ + 1], A2 = U[j0_ + 2];
                u16 e0 = par_ ? (u16)(A0 >> 16) : (u16)A0;
                u16 e1 = par_ ? (u16)A1         : (u16)(A0 >> 16);
                u16 e2 = par_ ? (u16)(A1 >> 16) : (u16)A1;
                u16 e3 = par_ ? (u16)A2         : (u16)(A1 >> 16);
                u16 e4 = par_ ? (u16)(A2 >> 16) : (u16)A2;
                tap[r * 5 + 0] = e0; tap[r * 5 + 1] = e1; tap[r * 5 + 2] = e2;
                tap[r * 5 + 3] = e3; tap[r * 5 + 4] = e4;
            }
            u32 ow[16];
#pragma unroll
            for (int j = 0; j < 12; ++j)
                ow[j] = (u32)tap[2 * j] | ((u32)tap[2 * j + 1] << 16);
            ow[12] = (u32)tap[24];
            ow[13] = 0u; ow[14] = 0u; ow[15] = 0u;
            u32* dst = (u32*)&im2[p_ * 40];
            *(uint4*)&dst[0]  = make_uint4(ow[0],  ow[1],  ow[2],  ow[3]);
            *(uint4*)&dst[4]  = make_uint4(ow[4],  ow[5],  ow[6],  ow[7]);
            *(uint4*)&dst[8]  = make_uint4(ow[8],  ow[9],  ow[10], ow[11]);
            *(uint4*)&dst[12] = make_uint4(ow[12], ow[13], ow[14], ow[15]);
        }
        __syncthreads();
        // 7 m-tiles: wave w takes mt = w and (w+4 if w<3); nt = 2
#pragma unroll
        for (int mi = 0; mi < 2; ++mi) {
            int mt = w + 4 * mi;
            if (mt < 7) {
                short8 af = *(const short8*)&im2[(mt * 16 + r16) * 40 + q * 8];
                floatx4 a1[2] = {};
#pragma unroll
                for (int nt = 0; nt < 2; ++nt)
                    a1[nt] = __builtin_amdgcn_mfma_f32_16x16x32_bf16(
                        af, w1f[nt], a1[nt], 0, 0, 0);
                int pq = mt * 4 + q;     // pooled col 0..27
#pragma unroll
                for (int nt = 0; nt < 2; ++nt) {
                    int oc = nt * 16 + r16;
                    if (oc < 20) {
                        floatx4 a = a1[nt];
                        float v = fmaxf(fmaxf(a[0], a[1]), fmaxf(a[2], a[3]))
                                + b1[oc];
                        h1t[(c * 28 + pq) * 40 + oc] = f2bf(v);
                    }
                }
            }
        }
        __syncthreads();
    }

    // ---- conv2 via MFMA: M=288 Z-ordered pre-pool, N=64, K=32, 25 taps ----
    int abase[5];
#pragma unroll
    for (int i = 0; i < 5; ++i) {
        int mt = w + 4 * i;
        if (mt < 18) {
            int m  = mt * 16 + r16;
            int pq = m >> 2, sub = m & 3;
            int py = pq / 12, px = pq - py * 12;
            int yy = py * 2 + (sub >> 1);
            int xx = px * 2 + (sub & 1);
            abase[i] = (yy * 28 + xx) * 40 + q * 8;
        } else abase[i] = 0;
    }
    floatx4 acc2[5][4] = {};
    const u16* wtb = w2t + r16 * 32 + q * 8;

    short8 bf[4];
#pragma unroll
    for (int nt = 0; nt < 4; ++nt)
        bf[nt] = *(const short8*)&wtb[nt * 512];

#pragma unroll 1
    for (int tap = 0; tap < 25; ++tap) {
        short8 bfn[4];
        if (tap < 24) {
#pragma unroll
            for (int nt = 0; nt < 4; ++nt)
                bfn[nt] = *(const short8*)&wtb[(tap + 1) * 2048 + nt * 512];
        }
        int r = tap / 5, s = tap - 5 * r;
        int aoff = r * 1120 + s * 40;
#pragma unroll
        for (int i = 0; i < 5; ++i) {
            int mt = w + 4 * i;
            if (mt < 18) {
                short8 af = *(const short8*)&h1t[abase[i] + aoff];
#pragma unroll
                for (int nt = 0; nt < 4; ++nt)
                    acc2[i][nt] = __builtin_amdgcn_mfma_f32_16x16x32_bf16(
                        af, bf[nt], acc2[i][nt], 0, 0, 0);
            }
        }
#pragma unroll
        for (int nt = 0; nt < 4; ++nt) bf[nt] = bfn[nt];
    }
    __syncthreads();  // all A-reads of h1t done; reuse as f32 out-stage

    // pool -> hs2[pos*50 + oc] (position-major)
    float* hs2 = (float*)h1t;  // 3600 f32
#pragma unroll
    for (int i = 0; i < 5; ++i) {
        int mt = w + 4 * i;
        if (mt < 18) {
            int pq = mt * 4 + q;   // = pos
#pragma unroll
            for (int nt = 0; nt < 4; ++nt) {
                int oc = nt * 16 + r16;
                if (oc < 50) {
                    floatx4 a = acc2[i][nt];
                    float v = fmaxf(fmaxf(a[0], a[1]), fmaxf(a[2], a[3])) + b2[oc];
                    hs2[pq * 50 + oc] = v;
                }
            }
        }
    }
    __syncthreads();
    // pack to bf16 (zero tail 3600..3615)
    u32* ho = h_bf + (size_t)b * 1808;
    for (int i = t; i < 1808; i += 256) {
        int i2 = 2 * i;
        u32 lo = (i2 < 3600) ? f2bf(hs2[i2]) : 0u;
        u32 hi = (i2 + 1 < 3600) ? f2bf(hs2[i2 + 1]) : 0u;
        ho[i] = lo | (hi << 16);
    }
}

// ---------- Kernel 2: pcaps (bf16 MFMA) + squash + priors + routing --------
__global__ __launch_bounds__(256) void k_pcaps(
    const u32* __restrict__ h_bf, const u16* __restrict__ w_pc,
    const float* __restrict__ pcb, const float* __restrict__ rw,
    float* __restrict__ cbuf)
{
    __shared__ __align__(16) u16 hsbuf[12672];  // 176 rows x 72 shorts
    __shared__ __align__(16) float pri[576];
    const int t = threadIdx.x;
    const int b = blockIdx.x;

    for (int i = t; i < 6336; i += 256) ((u32*)hsbuf)[i] = 0u;
    __syncthreads();
    {
        const u32* hb = h_bf + (size_t)b * 1808;
        for (int i = t; i < 1800; i += 256) {
            u32 v   = hb[i];
            int k2  = 2 * i;
            int pos = k2 / 50;
            int oc  = k2 - 50 * pos;
            int ph  = pos / 12, pw = pos - 12 * ph;
            ((u32*)hsbuf)[((((ph + 2) * 16) + pw + 2) * 72 + oc) >> 1] = v;
        }
    }
    __syncthreads();

    const int lane = t & 63, w = t >> 6;
    const int r16  = lane & 15;
    const int q    = lane >> 4;
    int abase[5];
#pragma unroll
    for (int mt = 0; mt < 5; ++mt) {
        int m  = mt * 16 + r16;
        int ph = m / 12, pw = m - 12 * ph;
        abase[mt] = (ph * 16 + pw) * 72 + q * 8;
    }
    floatx4 acc[5] = {};
    const u16* wp = w_pc + r16 * 64 + q * 8;
    const int ntap = (28 - w) >> 2;   // 7,6,6,6
#pragma unroll 1
    for (int tt = 0; tt < ntap; ++tt) {
        int tap = w + 4 * tt;
        short8 b0 = *(const short8*)&wp[tap * 1024];
        short8 b1 = *(const short8*)&wp[tap * 1024 + 32];
        int r = tap / 5, s = tap - 5 * r;
        int aoff = (r * 16 + s) * 72;
#pragma unroll
        for (int mt = 0; mt < 5; ++mt) {
            short8 a0 = *(const short8*)&hsbuf[abase[mt] + aoff];
            short8 a1 = *(const short8*)&hsbuf[abase[mt] + aoff + 32];
            acc[mt] = __builtin_amdgcn_mfma_f32_16x16x32_bf16(a0, b0, acc[mt], 0, 0, 0);
            acc[mt] = __builtin_amdgcn_mfma_f32_16x16x32_bf16(a1, b1, acc[mt], 0, 0, 0);
        }
    }
    __syncthreads();

    float* psum = (float*)hsbuf;
#pragma unroll
    for (int mt = 0; mt < 5; ++mt)
#pragma unroll
        for (int i = 0; i < 4; ++i) {
            int m = mt * 16 + q * 4 + i;
            psum[w * 1280 + m * 16 + r16] = acc[mt][i];
        }
    __syncthreads();

    for (int i = t; i < 1152; i += 256) {
        float s = psum[i] + psum[1280 + i] + psum[2560 + i] + psum[3840 + i]
                + pcb[i & 15];
        psum[i] = s;
    }
    __syncthreads();

    for (int r = t; r < 288; r += 256) {
        int sub = r / 72;
        int pos = r - sub * 72;
        float u0 = psum[pos * 16 + 0  + sub];
        float u1 = psum[pos * 16 + 4  + sub];
        float u2 = psum[pos * 16 + 8  + sub];
        float u3 = psum[pos * 16 + 12 + sub];
        float n2 = u0 * u0 + u1 * u1 + u2 * u2 + u3 * u3;
        float scale = (n2 / (1.0f + n2)) * rsqrtf(n2);
        u0 *= scale; u1 *= scale; u2 *= scale; u3 *= scale;
#pragma unroll
        for (int k = 0; k < 2; ++k) {
            const float4 wv = *(const float4*)&rw[(k * 288 + r) * 4];
            pri[k * 288 + r] = u0 * wv.x + u1 * wv.y + u2 * wv.z + u3 * wv.w;
        }
    }
    __syncthreads();

    if (w < 2) {
        const float* pr = &pri[w * 288];
        float p[5];
        bool  val[5];
#pragma unroll
        for (int j = 0; j < 5; ++j) {
            int r  = j * 64 + lane;
            val[j] = r < 288;
            p[j]   = val[j] ? pr[r] : 0.0f;
        }
        float tot = wave_sum(p[0] + p[1] + p[2] + p[3] + p[4]);
        float s = tot * (1.0f / 288.0f);
        float a = s * fabsf(s) / (1.0f + s * s);
#pragma unroll
        for (int it = 0; it < 2; ++it) {
            float l[5];
            float lm = -INFINITY;
#pragma unroll
            for (int j = 0; j < 5; ++j) {
                l[j] = val[j] ? p[j] * a : -INFINITY;
                lm   = fmaxf(lm, l[j]);
            }
            lm = wave_max(lm);
            float se = 0.f, sp = 0.f;
#pragma unroll
            for (int j = 0; j < 5; ++j) {
                float e = val[j] ? expf(l[j] - lm) : 0.f;
                se += e;
                sp += e * p[j];
            }
            se = wave_sum(se);
            sp = wave_sum(sp);
            float sv = sp / se;
            float v  = sv * fabsf(sv) / (1.0f + sv * sv);
            if (it == 0) a += v;
            else if (lane == 0) cbuf[b * 2 + w] = v;
        }
    }
}

// ---------- Kernel 4: fc1 bf16 MFMA GEMM [2048,3616]x[512,3616]^T ----------
__global__ __launch_bounds__(256) void k_fc1(
    const u16* __restrict__ h_bf, const u16* __restrict__ w_bf,
    const float* __restrict__ cc, const float* __restrict__ w,
    const float* __restrict__ bias, float* __restrict__ f1)
{
    __shared__ __align__(16) u16 As[64 * 40];
    __shared__ __align__(16) u16 Bs[64 * 40];
    const int t  = threadIdx.x;
    const int m0 = blockIdx.x * 64;
    const int n0 = blockIdx.y * 64;
    const int row = t >> 2, c8 = (t & 3) * 8;
    const u16* ha = &h_bf[(size_t)(m0 + row) * 3616 + c8];
    const u16* wa = &w_bf[(size_t)(n0 + row) * 3616 + c8];
    short8 areg = *(const short8*)ha;
    short8 breg = *(const short8*)wa;
    const int lane = t & 63, wv = t >> 6;
    const int r16 = lane & 15, q = lane >> 4;
    const int wr = row * 40 + (t & 3) * 8;
    const int ar = (wv * 16 + r16) * 40 + q * 8;
    const int br = r16 * 40 + q * 8;
    floatx4 acc[4] = {};
#pragma unroll 1
    for (int it = 0; it < 113; ++it) {
        __syncthreads();
        *(short8*)&As[wr] = areg;
        *(short8*)&Bs[wr] = breg;
        __syncthreads();
        if (it < 112) {
            areg = *(const short8*)(ha + (it + 1) * 32);
            breg = *(const short8*)(wa + (it + 1) * 32);
        }
        short8 af = *(const short8*)&As[ar];
#pragma unroll
        for (int nt = 0; nt < 4; ++nt) {
            short8 bfv = *(const short8*)&Bs[nt * 640 + br];
            acc[nt] = __builtin_amdgcn_mfma_f32_16x16x32_bf16(af, bfv, acc[nt], 0, 0, 0);
        }
    }
    const int mbase = m0 + wv * 16 + q * 4;
#pragma unroll
    for (int nt = 0; nt < 4; ++nt) {
        int n = n0 + nt * 16 + r16;
        if (n < 500) {
            float bn  = bias[n];
            float wc0 = w[(size_t)n * 3602 + 3600];
            float wc1 = w[(size_t)n * 3602 + 3601];
#pragma unroll
            for (int i = 0; i < 4; ++i) {
                int m = mbase + i;
                float v = acc[nt][i] + bn + cc[m * 2] * wc0 + cc[m * 2 + 1] * wc1;
                f1[(size_t)m * 500 + n] = fmaxf(v, 0.f);
            }
        }
    }
}

// ---------- Kernel 5: fc2, one wave per (b,j) ------------------------------
__global__ __launch_bounds__(256) void k_fc2(
    const float* __restrict__ f1, const float* __restrict__ y,
    const float* __restrict__ w, const float* __restrict__ bias,
    float* __restrict__ out)
{
    int wg   = blockIdx.x * 4 + (threadIdx.x >> 6);
    int lane = threadIdx.x & 63;
    int b = wg >> 1, j = wg & 1;
    const float* wj = w + j * 502;
    float acc = 0.f;
    for (int k = lane; k < 500; k += 64) acc += f1[(size_t)b * 500 + k] * wj[k];
    if (lane < 2) acc += y[b * 2 + lane] * wj[500 + lane];
    acc = wave_sum(acc);
    if (lane == 0) out[b * 2 + j] = acc + bias[j];
}

// ---------------------------------------------------------------------------
extern "C" void kernel_launch(void* const* d_in, const int* in_sizes, int n_in,
                              void* d_out, int out_size, void* d_ws, size_t ws_size,
                              hipStream_t stream) {
    const float* x    = (const float*)d_in[0];
    const float* y    = (const float*)d_in[1];
    const float* c1w  = (const float*)d_in[2];
    const float* c1b  = (const float*)d_in[3];
    const float* c2w  = (const float*)d_in[4];
    const float* c2b  = (const float*)d_in[5];
    const float* pcw  = (const float*)d_in[6];
    const float* pcb  = (const float*)d_in[7];
    const float* rw   = (const float*)d_in[8];
    const float* f1w  = (const float*)d_in[9];
    const float* f1b  = (const float*)d_in[10];
    const float* f2w  = (const float*)d_in[11];
    const float* f2b  = (const float*)d_in[12];
    float* out = (float*)d_out;

    // workspace layout
    u32*   h_bf   = (u32*)d_ws;                           // 2048*1808 u32
    u16*   w_bf   = (u16*)(h_bf + (size_t)BATCH * 1808);  // 512*3616 u16
    u16*   w2t    = w_bf + (size_t)512 * 3616;            // 25*64*32 u16
    u16*   w_pc   = w2t + 51200;                          // 25*16*64 u16
    u16*   w1t    = w_pc + 25600;                         // 32*32 u16
    float* cbuf   = (float*)(w1t + 1024);                 // 4096 f32
    float* f1     = cbuf + BATCH * 2;                     // 2048*500 f32

    k_prep<<<943, 256, 0, stream>>>(f1w, w_bf, c2w, w2t, pcw, w_pc, c1w, w1t);
    k_convs<<<BATCH, 256, 0, stream>>>(x, w1t, c1b, w2t, c2b, h_bf);
    k_pcaps<<<BATCH, 256, 0, stream>>>(h_bf, w_pc, pcb, rw, cbuf);
    dim3 g4(32, 8);
    k_fc1<<<g4, 256, 0, stream>>>((const u16*)h_bf, w_bf, cbuf, f1w, f1b, f1);
    k_fc2<<<BATCH * 2 / 4, 256, 0, stream>>>(f1, y, f2w, f2b, out);
}

// Round 8
// 259.068 us; speedup vs baseline: 6.5713x; 1.0463x over previous
//
#include <hip/hip_runtime.h>
#include <math.h>

// ---------------------------------------------------------------------------
// Model: conv1(5x5,20)+pool2 -> conv2(5x5,50)+pool2 -> pcaps(5x5 pad2,16)
//        -> squash -> priors -> dynamic routing(3) -> fc1(relu) -> fc2
// B=2048. conv1/conv2/pcaps/fc1 via bf16 MFMA (16x16x32).
// 3 kernels: k_prep (weights + out init), k_convs (conv1+conv2+pcaps+routing,
// one block per batch), k_fc1 (GEMM + fused fc2 epilogue via atomics).
// h_bf global layout POSITION-MAJOR: k' = pos*50 + oc, padded to 3616.
// ---------------------------------------------------------------------------

#define BATCH 2048

typedef __attribute__((ext_vector_type(8))) short short8;
typedef __attribute__((ext_vector_type(4))) float floatx4;
typedef unsigned short u16;
typedef unsigned int   u32;

__device__ inline float wave_sum(float v) {
#pragma unroll
    for (int off = 32; off >= 1; off >>= 1) v += __shfl_xor(v, off);
    return v;
}
__device__ inline float wave_max(float v) {
#pragma unroll
    for (int off = 32; off >= 1; off >>= 1) v = fmaxf(v, __shfl_xor(v, off));
    return v;
}
__device__ inline u16 f2bf(float f) {  // RNE fp32->bf16 (finite)
    u32 u = __float_as_uint(f);
    u32 r = (u + 0x7FFFu + ((u >> 16) & 1u)) >> 16;
    return (u16)r;
}

// ---------- Kernel 0: weight conversions + out init ------------------------
// blk <  500 : fc1 weights row n -> w_bf[n][3616] bf16, K-permuted, via LDS
// blk == 500 : zero w_bf rows 500..511
// blk <  526 : conv2 weights -> w2t[25][64][32] bf16
// blk <  539 : pcaps weights -> w_pc[25][16][64] bf16
// blk == 539 : conv1 weights -> w1t[32][32] bf16
// blk <  548 : out[b][j] = f2b[j] + y[b,0]*f2w[j,500] + y[b,1]*f2w[j,501]
__global__ __launch_bounds__(256) void k_prep(
    const float* __restrict__ fw,  u16* __restrict__ w_bf,
    const float* __restrict__ w2,  u16* __restrict__ w2t,
    const float* __restrict__ pcw, u16* __restrict__ w_pc,
    const float* __restrict__ w1,  u16* __restrict__ w1t,
    const float* __restrict__ y,   const float* __restrict__ f2w,
    const float* __restrict__ f2b, float* __restrict__ out)
{
    __shared__ __align__(16) float srow[3600];
    const int blk = blockIdx.x, t = threadIdx.x;
    if (blk < 500) {
        const int n = blk;
        const float* src = fw + (size_t)n * 3602;
        for (int i = t; i < 1800; i += 256)
            *(float2*)&srow[2 * i] = *(const float2*)&src[2 * i];
        __syncthreads();
        u32* dst = (u32*)(w_bf + (size_t)n * 3616);
        for (int i = t; i < 1808; i += 256) {
            int k2 = 2 * i;
            u32 pk = 0u;
            if (k2 < 3600) {
                int pos = k2 / 50, oc = k2 - 50 * pos;
                pk = (u32)f2bf(srow[oc * 72 + pos])
                   | ((u32)f2bf(srow[(oc + 1) * 72 + pos]) << 16);
            }
            dst[i] = pk;
        }
    } else if (blk == 500) {
        u32* z = (u32*)(w_bf + (size_t)500 * 3616);
        for (int i = t; i < 21696; i += 256) z[i] = 0u;
    } else if (blk < 526) {
        int g   = (blk - 501) * 256 + t;
        int idx = g * 8;
        int tap = idx >> 11;
        int oc  = (idx >> 5) & 63;
        int ic0 = idx & 31;
        u16 v[8];
#pragma unroll
        for (int j = 0; j < 8; ++j) {
            int ic = ic0 + j;
            float f = (ic < 20 && oc < 50) ? w2[oc * 500 + ic * 25 + tap] : 0.f;
            v[j] = f2bf(f);
        }
        *(short8*)&w2t[idx] = *(short8*)v;
    } else if (blk < 539) {
        int g = (blk - 526) * 256 + t;
        if (g >= 3200) return;
        int idx = g * 8;
        int tap = idx >> 10;
        int rem = idx & 1023;
        int oc  = rem >> 6;
        int ic0 = rem & 63;
        u16 v[8];
#pragma unroll
        for (int j = 0; j < 8; ++j) {
            int ic = ic0 + j;
            float f = (ic < 50) ? pcw[(oc * 50 + ic) * 25 + tap] : 0.f;
            v[j] = f2bf(f);
        }
        *(short8*)&w_pc[idx] = *(short8*)v;
    } else if (blk == 539) {
        if (t < 128) {
            int n  = t >> 2;
            int k0 = (t & 3) * 8;
            u16 v[8];
#pragma unroll
            for (int j = 0; j < 8; ++j) {
                int k = k0 + j;
                float f = (n < 20 && k < 25) ? w1[n * 25 + k] : 0.f;
                v[j] = f2bf(f);
            }
            *(short8*)&w1t[t * 8] = *(short8*)v;
        }
    } else {
        int b = (blk - 540) * 256 + t;   // 0..2047
        float y0 = y[b * 2], y1 = y[b * 2 + 1];
        float2 o;
        o.x = f2b[0] + y0 * f2w[500] + y1 * f2w[501];
        o.y = f2b[1] + y0 * f2w[502 + 500] + y1 * f2w[502 + 501];
        *(float2*)&out[b * 2] = o;
    }
}

// ---------- Kernel 1: conv1+conv2 (MFMA) + pcaps (MFMA) + routing ----------
// x:[B,1,36,60]; w1t:[32][32]; b1:[20]; w2t:[25][64][32]; b2:[50];
// w_pc:[25][16][64]; pcb:[16]; rw:[2,288,4]
// outputs: h_bf:[B][3616] bf16 pos-major; cbuf:[B][2] f32
// LDS (49408 B union):
//   conv phase : h1t[448][40] u16 | xbf[36][64] u16 | im2[112][40] u16
//   pcaps phase: hs2 f32[3600] @0 | hsbuf u16[12672] @7200 | pri f32[576] @19872
//                psum f32[5120] overlays hsbuf after MFMA
__global__ __launch_bounds__(256, 3) void k_convs(
    const float* __restrict__ x, const u16* __restrict__ w1t,
    const float* __restrict__ b1, const u16* __restrict__ w2t,
    const float* __restrict__ b2, const u16* __restrict__ w_pc,
    const float* __restrict__ pcb, const float* __restrict__ rw,
    u32* __restrict__ h_bf, float* __restrict__ cbuf)
{
    __shared__ __align__(16) u16 smem[24704];
    u16* h1t = smem;            // 17920 shorts
    u16* xbf = smem + 17920;    // 2304 shorts
    u16* im2 = smem + 20224;    // 4480 shorts

    const int t = threadIdx.x;
    const int b = blockIdx.x;

    // zero the ic pad [20,32) of h1t rows; stage x as bf16
    for (int i = t; i < 2688; i += 256) {
        int pos = i / 6, c = i - 6 * pos;
        ((u32*)h1t)[pos * 20 + 10 + c] = 0u;
    }
    const float* xb = x + b * 2160;
    for (int i = t; i < 2160; i += 256) {
        int r = i / 60, c = i - 60 * r;
        xbf[r * 64 + c] = f2bf(xb[i]);
    }
    __syncthreads();

    const int lane = t & 63, w = t >> 6;
    const int r16  = lane & 15;
    const int q    = lane >> 4;

    // ---- conv1 via MFMA, 16 chunks of 2 pre-pool rows (112 positions) ----
    short8 w1f[2];
#pragma unroll
    for (int nt = 0; nt < 2; ++nt)
        w1f[nt] = *(const short8*)&w1t[(nt * 16 + r16) * 32 + q * 8];

    const int p_   = t;               // builder position (t<112)
    const int px_  = p_ >> 2;
    const int dy_  = (p_ & 3) >> 1, dx_ = p_ & 1;
    const int xc_  = 2 * px_ + dx_;
    const int j0_  = xc_ >> 1;
    const int par_ = xc_ & 1;

#pragma unroll 1
    for (int c = 0; c < 16; ++c) {
        if (t < 112) {
            u16 tap[25];
#pragma unroll
            for (int r = 0; r < 5; ++r) {
                const u32* U = (const u32*)&xbf[(2 * c + dy_ + r) * 64];
                u32 A0 = U[j0_], A1 = U[j0_ + 1], A2 = U[j0_ + 2];
                u16 e0 = par_ ? (u16)(A0 >> 16) : (u16)A0;
                u16 e1 = par_ ? (u16)A1         : (u16)(A0 >> 16);
                u16 e2 = par_ ? (u16)(A1 >> 16) : (u16)A1;
                u16 e3 = par_ ? (u16)A2         : (u16)(A1 >> 16);
                u16 e4 = par_ ? (u16)(A2 >> 16) : (u16)A2;
                tap[r * 5 + 0] = e0; tap[r * 5 + 1] = e1; tap[r * 5 + 2] = e2;
                tap[r * 5 + 3] = e3; tap[r * 5 + 4] = e4;
            }
            u32 ow[16];
#pragma unroll
            for (int j = 0; j < 12; ++j)
                ow[j] = (u32)tap[2 * j] | ((u32)tap[2 * j + 1] << 16);
            ow[12] = (u32)tap[24];
            ow[13] = 0u; ow[14] = 0u; ow[15] = 0u;
            u32* dst = (u32*)&im2[p_ * 40];
            *(uint4*)&dst[0]  = make_uint4(ow[0],  ow[1],  ow[2],  ow[3]);
            *(uint4*)&dst[4]  = make_uint4(ow[4],  ow[5],  ow[6],  ow[7]);
            *(uint4*)&dst[8]  = make_uint4(ow[8],  ow[9],  ow[10], ow[11]);
            *(uint4*)&dst[12] = make_uint4(ow[12], ow[13], ow[14], ow[15]);
        }
        __syncthreads();
#pragma unroll
        for (int mi = 0; mi < 2; ++mi) {
            int mt = w + 4 * mi;
            if (mt < 7) {
                short8 af = *(const short8*)&im2[(mt * 16 + r16) * 40 + q * 8];
                floatx4 a1[2] = {};
#pragma unroll
                for (int nt = 0; nt < 2; ++nt)
                    a1[nt] = __builtin_amdgcn_mfma_f32_16x16x32_bf16(
                        af, w1f[nt], a1[nt], 0, 0, 0);
                int pq = mt * 4 + q;
#pragma unroll
                for (int nt = 0; nt < 2; ++nt) {
                    int oc = nt * 16 + r16;
                    if (oc < 20) {
                        floatx4 a = a1[nt];
                        float v = fmaxf(fmaxf(a[0], a[1]), fmaxf(a[2], a[3]))
                                + b1[oc];
                        h1t[(c * 28 + pq) * 40 + oc] = f2bf(v);
                    }
                }
            }
        }
        __syncthreads();
    }

    // ---- conv2 via MFMA: M=288 Z-ordered pre-pool, N=64, K=32, 25 taps ----
    int abase[5];
#pragma unroll
    for (int i = 0; i < 5; ++i) {
        int mt = w + 4 * i;
        if (mt < 18) {
            int m  = mt * 16 + r16;
            int pq = m >> 2, sub = m & 3;
            int py = pq / 12, px = pq - py * 12;
            int yy = py * 2 + (sub >> 1);
            int xx = px * 2 + (sub & 1);
            abase[i] = (yy * 28 + xx) * 40 + q * 8;
        } else abase[i] = 0;
    }
    floatx4 acc2[5][4] = {};
    const u16* wtb = w2t + r16 * 32 + q * 8;

    short8 bf[4];
#pragma unroll
    for (int nt = 0; nt < 4; ++nt)
        bf[nt] = *(const short8*)&wtb[nt * 512];

#pragma unroll 1
    for (int tap = 0; tap < 25; ++tap) {
        short8 bfn[4];
        if (tap < 24) {
#pragma unroll
            for (int nt = 0; nt < 4; ++nt)
                bfn[nt] = *(const short8*)&wtb[(tap + 1) * 2048 + nt * 512];
        }
        int r = tap / 5, s = tap - 5 * r;
        int aoff = r * 1120 + s * 40;
#pragma unroll
        for (int i = 0; i < 5; ++i) {
            int mt = w + 4 * i;
            if (mt < 18) {
                short8 af = *(const short8*)&h1t[abase[i] + aoff];
#pragma unroll
                for (int nt = 0; nt < 4; ++nt)
                    acc2[i][nt] = __builtin_amdgcn_mfma_f32_16x16x32_bf16(
                        af, bf[nt], acc2[i][nt], 0, 0, 0);
            }
        }
#pragma unroll
        for (int nt = 0; nt < 4; ++nt) bf[nt] = bfn[nt];
    }
    __syncthreads();  // all A-reads of h1t done; overlay pcaps buffers

    // ---- pool -> hs2[pos*50+oc] f32 @smem[0]; zero hsbuf region @7200 ----
    float* hs2 = (float*)smem;  // 3600 f32
#pragma unroll
    for (int i = 0; i < 5; ++i) {
        int mt = w + 4 * i;
        if (mt < 18) {
            int pq = mt * 4 + q;
#pragma unroll
            for (int nt = 0; nt < 4; ++nt) {
                int oc = nt * 16 + r16;
                if (oc < 50) {
                    floatx4 a = acc2[i][nt];
                    float v = fmaxf(fmaxf(a[0], a[1]), fmaxf(a[2], a[3])) + b2[oc];
                    hs2[pq * 50 + oc] = v;
                }
            }
        }
    }
    for (int i = t; i < 6336; i += 256)   // zero hsbuf [7200,19872) shorts
        ((u32*)smem)[3600 + i] = 0u;
    __syncthreads();

    // ---- pack h_bf (global, for fc1) + fill hsbuf interior ----
    u16* hsbuf = smem + 7200;             // [176][72] bf16, borders zero
    u32* ho = h_bf + (size_t)b * 1808;
    for (int i = t; i < 1808; i += 256) {
        if (i < 1800) {
            int k2 = 2 * i;
            u32 pk = (u32)f2bf(hs2[k2]) | ((u32)f2bf(hs2[k2 + 1]) << 16);
            ho[i] = pk;
            int pos = k2 / 50;
            int oc  = k2 - 50 * pos;      // even
            int ph  = pos / 12, pw = pos - 12 * ph;
            ((u32*)hsbuf)[((((ph + 2) * 16) + pw + 2) * 72 + oc) >> 1] = pk;
        } else ho[i] = 0u;
    }
    __syncthreads();

    // ---- pcaps via MFMA: M=72 pos (5 m-tiles), N=16 oc, K=64, taps/wave ----
    int pbase[5];
#pragma unroll
    for (int mt = 0; mt < 5; ++mt) {
        int m  = mt * 16 + r16;
        int ph = m / 12, pw = m - 12 * ph;
        pbase[mt] = (ph * 16 + pw) * 72 + q * 8;
    }
    floatx4 pacc[5] = {};
    const u16* wp = w_pc + r16 * 64 + q * 8;
    const int ntap = (28 - w) >> 2;       // 7,6,6,6
#pragma unroll 1
    for (int tt = 0; tt < ntap; ++tt) {
        int tap = w + 4 * tt;
        short8 b0 = *(const short8*)&wp[tap * 1024];
        short8 b1 = *(const short8*)&wp[tap * 1024 + 32];
        int r = tap / 5, s = tap - 5 * r;
        int aoff = (r * 16 + s) * 72;
#pragma unroll
        for (int mt = 0; mt < 5; ++mt) {
            short8 a0 = *(const short8*)&hsbuf[pbase[mt] + aoff];
            short8 a1 = *(const short8*)&hsbuf[pbase[mt] + aoff + 32];
            pacc[mt] = __builtin_amdgcn_mfma_f32_16x16x32_bf16(a0, b0, pacc[mt], 0, 0, 0);
            pacc[mt] = __builtin_amdgcn_mfma_f32_16x16x32_bf16(a1, b1, pacc[mt], 0, 0, 0);
        }
    }
    __syncthreads();  // hsbuf reads done -> overlay psum

    float* psum = (float*)(smem + 7200);  // [4][80][16] f32
#pragma unroll
    for (int mt = 0; mt < 5; ++mt)
#pragma unroll
        for (int i = 0; i < 4; ++i) {
            int m = mt * 16 + q * 4 + i;
            psum[w * 1280 + m * 16 + r16] = pacc[mt][i];
        }
    __syncthreads();

    for (int i = t; i < 1152; i += 256) {
        float s = psum[i] + psum[1280 + i] + psum[2560 + i] + psum[3840 + i]
                + pcb[i & 15];
        psum[i] = s;
    }
    __syncthreads();

    // squash + priors -> pri[2][288]
    float* pri = (float*)(smem + 19872);
    for (int r = t; r < 288; r += 256) {
        int sub = r / 72;
        int pos = r - sub * 72;
        float u0 = psum[pos * 16 + 0  + sub];
        float u1 = psum[pos * 16 + 4  + sub];
        float u2 = psum[pos * 16 + 8  + sub];
        float u3 = psum[pos * 16 + 12 + sub];
        float n2 = u0 * u0 + u1 * u1 + u2 * u2 + u3 * u3;
        float scale = (n2 / (1.0f + n2)) * rsqrtf(n2);
        u0 *= scale; u1 *= scale; u2 *= scale; u3 *= scale;
#pragma unroll
        for (int k = 0; k < 2; ++k) {
            const float4 wv = *(const float4*)&rw[(k * 288 + r) * 4];
            pri[k * 288 + r] = u0 * wv.x + u1 * wv.y + u2 * wv.z + u3 * wv.w;
        }
    }
    __syncthreads();

    // dynamic routing (3 iters): wave 0 -> k=0, wave 1 -> k=1
    if (w < 2) {
        const float* pr = &pri[w * 288];
        float p[5];
        bool  val[5];
#pragma unroll
        for (int j = 0; j < 5; ++j) {
            int r  = j * 64 + lane;
            val[j] = r < 288;
            p[j]   = val[j] ? pr[r] : 0.0f;
        }
        float tot = wave_sum(p[0] + p[1] + p[2] + p[3] + p[4]);
        float s = tot * (1.0f / 288.0f);
        float a = s * fabsf(s) / (1.0f + s * s);
#pragma unroll
        for (int it = 0; it < 2; ++it) {
            float l[5];
            float lm = -INFINITY;
#pragma unroll
            for (int j = 0; j < 5; ++j) {
                l[j] = val[j] ? p[j] * a : -INFINITY;
                lm   = fmaxf(lm, l[j]);
            }
            lm = wave_max(lm);
            float se = 0.f, sp = 0.f;
#pragma unroll
            for (int j = 0; j < 5; ++j) {
                float e = val[j] ? expf(l[j] - lm) : 0.f;
                se += e;
                sp += e * p[j];
            }
            se = wave_sum(se);
            sp = wave_sum(sp);
            float sv = sp / se;
            float v  = sv * fabsf(sv) / (1.0f + sv * sv);
            if (it == 0) a += v;
            else if (lane == 0) cbuf[b * 2 + w] = v;
        }
    }
}

// ---------- Kernel 2: fc1 bf16 MFMA GEMM + fused fc2 epilogue --------------
// out[b][j] += sum_{n in this block} relu(fc1[b][n]) * f2w[j][n]  (atomic)
__global__ __launch_bounds__(256) void k_fc1(
    const u16* __restrict__ h_bf, const u16* __restrict__ w_bf,
    const float* __restrict__ cc, const float* __restrict__ w,
    const float* __restrict__ bias, const float* __restrict__ f2w,
    float* __restrict__ out)
{
    __shared__ __align__(16) u16 As[64 * 40];
    __shared__ __align__(16) u16 Bs[64 * 40];
    const int t  = threadIdx.x;
    const int m0 = blockIdx.x * 64;
    const int n0 = blockIdx.y * 64;
    const int row = t >> 2, c8 = (t & 3) * 8;
    const u16* ha = &h_bf[(size_t)(m0 + row) * 3616 + c8];
    const u16* wa = &w_bf[(size_t)(n0 + row) * 3616 + c8];
    short8 areg = *(const short8*)ha;
    short8 breg = *(const short8*)wa;
    const int lane = t & 63, wv = t >> 6;
    const int r16 = lane & 15, q = lane >> 4;
    const int wr = row * 40 + (t & 3) * 8;
    const int ar = (wv * 16 + r16) * 40 + q * 8;
    const int br = r16 * 40 + q * 8;
    floatx4 acc[4] = {};
#pragma unroll 1
    for (int it = 0; it < 113; ++it) {
        __syncthreads();
        *(short8*)&As[wr] = areg;
        *(short8*)&Bs[wr] = breg;
        __syncthreads();
        if (it < 112) {
            areg = *(const short8*)(ha + (it + 1) * 32);
            breg = *(const short8*)(wa + (it + 1) * 32);
        }
        short8 af = *(const short8*)&As[ar];
#pragma unroll
        for (int nt = 0; nt < 4; ++nt) {
            short8 bfv = *(const short8*)&Bs[nt * 640 + br];
            acc[nt] = __builtin_amdgcn_mfma_f32_16x16x32_bf16(af, bfv, acc[nt], 0, 0, 0);
        }
    }
    // epilogue: bias + caps cols + relu, then dot with fc2 rows
    const int mbase = m0 + wv * 16 + q * 4;
    float s0[4] = {0.f, 0.f, 0.f, 0.f};
    float s1[4] = {0.f, 0.f, 0.f, 0.f};
#pragma unroll
    for (int nt = 0; nt < 4; ++nt) {
        int n = n0 + nt * 16 + r16;
        if (n < 500) {
            float bn  = bias[n];
            float wc0 = w[(size_t)n * 3602 + 3600];
            float wc1 = w[(size_t)n * 3602 + 3601];
            float w20 = f2w[n];
            float w21 = f2w[502 + n];
#pragma unroll
            for (int i = 0; i < 4; ++i) {
                int m = mbase + i;
                float v = fmaxf(acc[nt][i] + bn + cc[m * 2] * wc0
                                + cc[m * 2 + 1] * wc1, 0.f);
                s0[i] += v * w20;
                s1[i] += v * w21;
            }
        }
    }
#pragma unroll
    for (int i = 0; i < 4; ++i) {
        float a0 = s0[i], a1 = s1[i];
#pragma unroll
        for (int off = 1; off <= 8; off <<= 1) {
            a0 += __shfl_xor(a0, off);
            a1 += __shfl_xor(a1, off);
        }
        if (r16 == 0) {
            int m = mbase + i;
            atomicAdd(&out[m * 2], a0);
            atomicAdd(&out[m * 2 + 1], a1);
        }
    }
}

// ---------------------------------------------------------------------------
extern "C" void kernel_launch(void* const* d_in, const int* in_sizes, int n_in,
                              void* d_out, int out_size, void* d_ws, size_t ws_size,
                              hipStream_t stream) {
    const float* x    = (const float*)d_in[0];
    const float* y    = (const float*)d_in[1];
    const float* c1w  = (const float*)d_in[2];
    const float* c1b  = (const float*)d_in[3];
    const float* c2w  = (const float*)d_in[4];
    const float* c2b  = (const float*)d_in[5];
    const float* pcw  = (const float*)d_in[6];
    const float* pcb  = (const float*)d_in[7];
    const float* rw   = (const float*)d_in[8];
    const float* f1w  = (const float*)d_in[9];
    const float* f1b  = (const float*)d_in[10];
    const float* f2w  = (const float*)d_in[11];
    const float* f2b  = (const float*)d_in[12];
    float* out = (float*)d_out;

    // workspace layout
    u32*   h_bf = (u32*)d_ws;                           // 2048*1808 u32
    u16*   w_bf = (u16*)(h_bf + (size_t)BATCH * 1808);  // 512*3616 u16
    u16*   w2t  = w_bf + (size_t)512 * 3616;            // 25*64*32 u16
    u16*   w_pc = w2t + 51200;                          // 25*16*64 u16
    u16*   w1t  = w_pc + 25600;                         // 32*32 u16
    float* cbuf = (float*)(w1t + 1024);                 // 4096 f32

    k_prep<<<548, 256, 0, stream>>>(f1w, w_bf, c2w, w2t, pcw, w_pc, c1w, w1t,
                                    y, f2w, f2b, out);
    k_convs<<<BATCH, 256, 0, stream>>>(x, w1t, c1b, w2t, c2b, w_pc, pcb, rw,
                                       h_bf, cbuf);
    dim3 g4(32, 8);
    k_fc1<<<g4, 256, 0, stream>>>((const u16*)h_bf, w_bf, cbuf, f1w, f1b,
                                  f2w, out);
}